// Round 1
// baseline (924.116 us; speedup 1.0000x reference)
//
#include <hip/hip_runtime.h>
#include <math.h>

// Problem constants (fixed by reference)
#define NN 50000
#define NE 800000
#define F_IN 128
#define F_HID 256
#define NG 64

// ---------------- GEMM: C[M,256] = A[M,K] @ B[K,256], fp32 ----------------
// 64x64 tile per block, 256 threads, 4x4 micro-tile per thread.
__global__ __launch_bounds__(256)
void gemm64(const float* __restrict__ A, const float* __restrict__ B,
            float* __restrict__ C, int M, int Ncols, int K) {
    __shared__ float As[16][65];   // [k][m], padded
    __shared__ float Bs[16][64];   // [k][n]
    int tid = threadIdx.x;
    int tx = tid & 15, ty = tid >> 4;
    int bm = blockIdx.x * 64, bn = blockIdx.y * 64;
    float acc[4][4] = {};
    for (int k0 = 0; k0 < K; k0 += 16) {
        int c = tid & 15, r0 = tid >> 4;
        #pragma unroll
        for (int q = 0; q < 4; ++q) {
            int r = r0 + q * 16;
            int gm = bm + r;
            As[c][r] = (gm < M) ? A[(size_t)gm * K + k0 + c] : 0.f;
        }
        int j = tid & 63, kr = tid >> 6;
        #pragma unroll
        for (int q = 0; q < 4; ++q) {
            int kk = kr + q * 4;
            Bs[kk][j] = B[(size_t)(k0 + kk) * Ncols + bn + j];
        }
        __syncthreads();
        #pragma unroll
        for (int k = 0; k < 16; ++k) {
            float a[4], b[4];
            #pragma unroll
            for (int i = 0; i < 4; ++i) a[i] = As[k][ty + 16 * i];
            #pragma unroll
            for (int jj = 0; jj < 4; ++jj) b[jj] = Bs[k][tx + 16 * jj];
            #pragma unroll
            for (int i = 0; i < 4; ++i)
                #pragma unroll
                for (int jj = 0; jj < 4; ++jj)
                    acc[i][jj] += a[i] * b[jj];
        }
        __syncthreads();
    }
    #pragma unroll
    for (int i = 0; i < 4; ++i) {
        int gm = bm + ty + 16 * i;
        if (gm >= M) continue;
        #pragma unroll
        for (int jj = 0; jj < 4; ++jj)
            C[(size_t)gm * Ncols + bn + tx + 16 * jj] = acc[i][jj];
    }
}

// --------- per-node attention dots: as[i]=h[i,:]·a_s, ad[i]=h[i,:]·a_d -----
__global__ __launch_bounds__(256)
void attn_dots(const float* __restrict__ h, const float* __restrict__ a_s,
               const float* __restrict__ a_d, float* __restrict__ as_out,
               float* __restrict__ ad_out, int n) {
    int wv = (int)((blockIdx.x * blockDim.x + threadIdx.x) >> 6);
    int lane = threadIdx.x & 63;
    if (wv >= n) return;
    const float4* hv = (const float4*)(h + (size_t)wv * 256);
    float4 x = hv[lane];
    float4 u = ((const float4*)a_s)[lane];
    float4 v = ((const float4*)a_d)[lane];
    float s1 = x.x * u.x + x.y * u.y + x.z * u.z + x.w * u.w;
    float s2 = x.x * v.x + x.y * v.y + x.z * v.z + x.w * v.w;
    #pragma unroll
    for (int off = 32; off; off >>= 1) {
        s1 += __shfl_xor(s1, off);
        s2 += __shfl_xor(s2, off);
    }
    if (lane == 0) { as_out[wv] = s1; ad_out[wv] = s2; }
}

// ---------------- CSR build ----------------
__global__ void init_counts(int* __restrict__ counts, int n) {
    int i = blockIdx.x * blockDim.x + threadIdx.x;
    if (i < n) counts[i] = 1;   // self-loop pre-seeded
}

__global__ void hist_kernel(const int* __restrict__ dst, int* __restrict__ counts, int E) {
    int e = blockIdx.x * blockDim.x + threadIdx.x;
    if (e < E) atomicAdd(&counts[dst[e]], 1);
}

__global__ void scan_kernel(const int* __restrict__ counts, int* __restrict__ offsets, int n) {
    __shared__ int part[1024];
    int tid = threadIdx.x;
    int chunk = (n + 1023) / 1024;
    int lo = tid * chunk;
    int hi = min(lo + chunk, n);
    int s = 0;
    for (int i = lo; i < hi; ++i) s += counts[i];
    part[tid] = s;
    __syncthreads();
    for (int d = 1; d < 1024; d <<= 1) {
        int v = (tid >= d) ? part[tid - d] : 0;
        __syncthreads();
        part[tid] += v;
        __syncthreads();
    }
    int run = (tid == 0) ? 0 : part[tid - 1];
    for (int i = lo; i < hi; ++i) { offsets[i] = run; run += counts[i]; }
    if (tid == 1023) offsets[n] = run;
}

__global__ void copy_cursor(const int* __restrict__ offsets, int* __restrict__ cursor, int n) {
    int i = blockIdx.x * blockDim.x + threadIdx.x;
    if (i < n) cursor[i] = offsets[i];
}

__global__ void scatter_kernel(const int* __restrict__ src, const int* __restrict__ dst,
                               int* __restrict__ cursor, int* __restrict__ src_sorted,
                               int E, int n) {
    int e = blockIdx.x * blockDim.x + threadIdx.x;
    if (e < E) {
        int d = dst[e];
        int pos = atomicAdd(&cursor[d], 1);
        src_sorted[pos] = src[e];
    } else if (e < E + n) {
        int i = e - E;
        int pos = atomicAdd(&cursor[i], 1);
        src_sorted[pos] = i;
    }
}

// ---------------- GAT aggregation: one wave per dst node ----------------
template <bool ACT>
__global__ __launch_bounds__(256)
void agg_kernel(const float* __restrict__ h, const float* __restrict__ as,
                const float* __restrict__ ad, const int* __restrict__ offsets,
                const int* __restrict__ src_sorted, const float* __restrict__ bias,
                float* __restrict__ out, int n) {
    int wv = (int)((blockIdx.x * blockDim.x + threadIdx.x) >> 6);
    int lane = threadIdx.x & 63;
    if (wv >= n) return;
    int start = offsets[wv], end = offsets[wv + 1];
    float adn = ad[wv];
    // pass 1: max
    float m = -INFINITY;
    for (int j = start + lane; j < end; j += 64) {
        int s = src_sorted[j];
        float e = as[s] + adn;
        e = e > 0.f ? e : 0.2f * e;
        m = fmaxf(m, e);
    }
    #pragma unroll
    for (int off = 32; off; off >>= 1) m = fmaxf(m, __shfl_xor(m, off));
    // pass 2: denom
    float denom = 0.f;
    for (int j = start + lane; j < end; j += 64) {
        int s = src_sorted[j];
        float e = as[s] + adn;
        e = e > 0.f ? e : 0.2f * e;
        denom += __expf(e - m);
    }
    #pragma unroll
    for (int off = 32; off; off >>= 1) denom += __shfl_xor(denom, off);
    float inv = 1.f / denom;
    // pass 3: weighted gather
    float4 acc = make_float4(0.f, 0.f, 0.f, 0.f);
    const float4* hv = (const float4*)h;
    for (int j = start; j < end; ++j) {
        int s = src_sorted[j];
        float e = as[s] + adn;
        e = e > 0.f ? e : 0.2f * e;
        float w = __expf(e - m) * inv;
        float4 x = hv[(size_t)s * 64 + lane];
        acc.x += w * x.x; acc.y += w * x.y; acc.z += w * x.z; acc.w += w * x.w;
    }
    float4 bv = ((const float4*)bias)[lane];
    acc.x += bv.x; acc.y += bv.y; acc.z += bv.z; acc.w += bv.w;
    if (ACT) {
        acc.x = acc.x > 0.f ? acc.x : 0.01f * acc.x;
        acc.y = acc.y > 0.f ? acc.y : 0.01f * acc.y;
        acc.z = acc.z > 0.f ? acc.z : 0.01f * acc.z;
        acc.w = acc.w > 0.f ? acc.w : 0.01f * acc.w;
    }
    ((float4*)out)[(size_t)wv * 64 + lane] = acc;
}

// ---------------- graph pooling (batch is sorted) ----------------
__global__ __launch_bounds__(256)
void pool_kernel(const float* __restrict__ node_emb, const int* __restrict__ batch,
                 float* __restrict__ graph_emb, int n) {
    int g = blockIdx.x;
    int f = threadIdx.x;
    int lo = 0, hi = n;
    while (lo < hi) { int mid = (lo + hi) >> 1; if (batch[mid] < g) lo = mid + 1; else hi = mid; }
    int s0 = lo;
    lo = 0; hi = n;
    while (lo < hi) { int mid = (lo + hi) >> 1; if (batch[mid] < g + 1) lo = mid + 1; else hi = mid; }
    int s1 = lo;
    float acc = 0.f;
    for (int i = s0; i < s1; ++i) acc += node_emb[(size_t)i * 256 + f];
    graph_emb[(size_t)g * 256 + f] = acc;
}

extern "C" void kernel_launch(void* const* d_in, const int* in_sizes, int n_in,
                              void* d_out, int out_size, void* d_ws, size_t ws_size,
                              hipStream_t stream) {
    const float* x     = (const float*)d_in[0];
    const int* eidx    = (const int*)d_in[1];   // [2, E]: row0=src, row1=dst
    const int* batch   = (const int*)d_in[2];
    const float* W1    = (const float*)d_in[3];
    const float* a_s1  = (const float*)d_in[4];
    const float* a_d1  = (const float*)d_in[5];
    const float* b1    = (const float*)d_in[6];
    const float* W2    = (const float*)d_in[7];
    const float* a_s2  = (const float*)d_in[8];
    const float* a_d2  = (const float*)d_in[9];
    const float* b2    = (const float*)d_in[10];

    float* node_emb  = (float*)d_out;                       // [NN, 256]
    float* graph_emb = node_emb + (size_t)NN * 256;         // [NG, 256]

    char* ws = (char*)d_ws;
    float* buf_h   = (float*)ws;               ws += (size_t)NN * 256 * sizeof(float);
    float* as_buf  = (float*)ws;               ws += (size_t)NN * sizeof(float);
    float* ad_buf  = (float*)ws;               ws += (size_t)NN * sizeof(float);
    int* counts    = (int*)ws;                 ws += (size_t)NN * sizeof(int);
    int* offsets   = (int*)ws;                 ws += (size_t)(NN + 1) * sizeof(int);
    int* cursor    = (int*)ws;                 ws += (size_t)NN * sizeof(int);
    int* src_sorted = (int*)ws;                ws += (size_t)(NE + NN) * sizeof(int);

    const int* e_src = eidx;
    const int* e_dst = eidx + NE;

    dim3 gemm_grid((NN + 63) / 64, 256 / 64);
    int node_waves_blocks = (NN + 3) / 4;   // 4 waves per 256-thread block

    // ---- CSR build (shared by both layers) ----
    init_counts<<<(NN + 255) / 256, 256, 0, stream>>>(counts, NN);
    hist_kernel<<<(NE + 255) / 256, 256, 0, stream>>>(e_dst, counts, NE);
    scan_kernel<<<1, 1024, 0, stream>>>(counts, offsets, NN);
    copy_cursor<<<(NN + 255) / 256, 256, 0, stream>>>(offsets, cursor, NN);
    scatter_kernel<<<(NE + NN + 255) / 256, 256, 0, stream>>>(e_src, e_dst, cursor, src_sorted, NE, NN);

    // ---- layer 1 ----
    gemm64<<<gemm_grid, 256, 0, stream>>>(x, W1, buf_h, NN, 256, F_IN);
    attn_dots<<<node_waves_blocks, 256, 0, stream>>>(buf_h, a_s1, a_d1, as_buf, ad_buf, NN);
    agg_kernel<true><<<node_waves_blocks, 256, 0, stream>>>(buf_h, as_buf, ad_buf, offsets,
                                                            src_sorted, b1, node_emb, NN);
    // ---- layer 2 (input = activated layer-1 output living in d_out) ----
    gemm64<<<gemm_grid, 256, 0, stream>>>(node_emb, W2, buf_h, NN, 256, F_HID);
    attn_dots<<<node_waves_blocks, 256, 0, stream>>>(buf_h, a_s2, a_d2, as_buf, ad_buf, NN);
    agg_kernel<false><<<node_waves_blocks, 256, 0, stream>>>(buf_h, as_buf, ad_buf, offsets,
                                                             src_sorted, b2, node_emb, NN);
    // ---- pool ----
    pool_kernel<<<NG, 256, 0, stream>>>(node_emb, batch, graph_emb, NN);
}

// Round 2
// 755.083 us; speedup vs baseline: 1.2239x; 1.2239x over previous
//
#include <hip/hip_runtime.h>
#include <math.h>

// Problem constants (fixed by reference)
#define NN 50000
#define NE 800000
#define F_IN 128
#define F_HID 256
#define NG 64

// ---------------- GEMM: C[M,256] = A[M,K] @ B[K,256], fp32 ----------------
// 64x64 tile per block, 256 threads, 4x4 micro-tile per thread.
__global__ __launch_bounds__(256)
void gemm64(const float* __restrict__ A, const float* __restrict__ B,
            float* __restrict__ C, int M, int Ncols, int K) {
    __shared__ float As[16][65];   // [k][m], padded
    __shared__ float Bs[16][64];   // [k][n]
    int tid = threadIdx.x;
    int tx = tid & 15, ty = tid >> 4;
    int bm = blockIdx.x * 64, bn = blockIdx.y * 64;
    float acc[4][4] = {};
    for (int k0 = 0; k0 < K; k0 += 16) {
        int c = tid & 15, r0 = tid >> 4;
        #pragma unroll
        for (int q = 0; q < 4; ++q) {
            int r = r0 + q * 16;
            int gm = bm + r;
            As[c][r] = (gm < M) ? A[(size_t)gm * K + k0 + c] : 0.f;
        }
        int j = tid & 63, kr = tid >> 6;
        #pragma unroll
        for (int q = 0; q < 4; ++q) {
            int kk = kr + q * 4;
            Bs[kk][j] = B[(size_t)(k0 + kk) * Ncols + bn + j];
        }
        __syncthreads();
        #pragma unroll
        for (int k = 0; k < 16; ++k) {
            float a[4], b[4];
            #pragma unroll
            for (int i = 0; i < 4; ++i) a[i] = As[k][ty + 16 * i];
            #pragma unroll
            for (int jj = 0; jj < 4; ++jj) b[jj] = Bs[k][tx + 16 * jj];
            #pragma unroll
            for (int i = 0; i < 4; ++i)
                #pragma unroll
                for (int jj = 0; jj < 4; ++jj)
                    acc[i][jj] += a[i] * b[jj];
        }
        __syncthreads();
    }
    #pragma unroll
    for (int i = 0; i < 4; ++i) {
        int gm = bm + ty + 16 * i;
        if (gm >= M) continue;
        #pragma unroll
        for (int jj = 0; jj < 4; ++jj)
            C[(size_t)gm * Ncols + bn + tx + 16 * jj] = acc[i][jj];
    }
}

// --------- per-node attention dots: as[i]=h[i,:]·a_s, ad[i]=h[i,:]·a_d -----
__global__ __launch_bounds__(256)
void attn_dots(const float* __restrict__ h, const float* __restrict__ a_s,
               const float* __restrict__ a_d, float* __restrict__ as_out,
               float* __restrict__ ad_out, int n) {
    int wv = (int)((blockIdx.x * blockDim.x + threadIdx.x) >> 6);
    int lane = threadIdx.x & 63;
    if (wv >= n) return;
    const float4* hv = (const float4*)(h + (size_t)wv * 256);
    float4 x = hv[lane];
    float4 u = ((const float4*)a_s)[lane];
    float4 v = ((const float4*)a_d)[lane];
    float s1 = x.x * u.x + x.y * u.y + x.z * u.z + x.w * u.w;
    float s2 = x.x * v.x + x.y * v.y + x.z * v.z + x.w * v.w;
    #pragma unroll
    for (int off = 32; off; off >>= 1) {
        s1 += __shfl_xor(s1, off);
        s2 += __shfl_xor(s2, off);
    }
    if (lane == 0) { as_out[wv] = s1; ad_out[wv] = s2; }
}

// ---------------- CSR build ----------------
__global__ void init_counts(int* __restrict__ counts, int n) {
    int i = blockIdx.x * blockDim.x + threadIdx.x;
    if (i < n) counts[i] = 1;   // self-loop pre-seeded
}

__global__ void hist_kernel(const int* __restrict__ dst, int* __restrict__ counts, int E) {
    int e = blockIdx.x * blockDim.x + threadIdx.x;
    if (e < E) atomicAdd(&counts[dst[e]], 1);
}

__global__ void scan_kernel(const int* __restrict__ counts, int* __restrict__ offsets, int n) {
    __shared__ int part[1024];
    int tid = threadIdx.x;
    int chunk = (n + 1023) / 1024;
    int lo = tid * chunk;
    int hi = min(lo + chunk, n);
    int s = 0;
    for (int i = lo; i < hi; ++i) s += counts[i];
    part[tid] = s;
    __syncthreads();
    for (int d = 1; d < 1024; d <<= 1) {
        int v = (tid >= d) ? part[tid - d] : 0;
        __syncthreads();
        part[tid] += v;
        __syncthreads();
    }
    int run = (tid == 0) ? 0 : part[tid - 1];
    for (int i = lo; i < hi; ++i) { offsets[i] = run; run += counts[i]; }
    if (tid == 1023) offsets[n] = run;
}

__global__ void copy_cursor(const int* __restrict__ offsets, int* __restrict__ cursor, int n) {
    int i = blockIdx.x * blockDim.x + threadIdx.x;
    if (i < n) cursor[i] = offsets[i];
}

__global__ void scatter_kernel(const int* __restrict__ src, const int* __restrict__ dst,
                               int* __restrict__ cursor, int* __restrict__ src_sorted,
                               int E, int n) {
    int e = blockIdx.x * blockDim.x + threadIdx.x;
    if (e < E) {
        int d = dst[e];
        int pos = atomicAdd(&cursor[d], 1);
        src_sorted[pos] = src[e];
    } else if (e < E + n) {
        int i = e - E;
        int pos = atomicAdd(&cursor[i], 1);
        src_sorted[pos] = i;
    }
}

// ---------------- GAT aggregation: one wave per dst node ----------------
template <bool ACT>
__global__ __launch_bounds__(256)
void agg_kernel(const float* __restrict__ h, const float* __restrict__ as,
                const float* __restrict__ ad, const int* __restrict__ offsets,
                const int* __restrict__ src_sorted, const float* __restrict__ bias,
                float* __restrict__ out, int n) {
    int wv = (int)((blockIdx.x * blockDim.x + threadIdx.x) >> 6);
    int lane = threadIdx.x & 63;
    if (wv >= n) return;
    int start = offsets[wv], end = offsets[wv + 1];
    float adn = ad[wv];
    // pass 1: max
    float m = -INFINITY;
    for (int j = start + lane; j < end; j += 64) {
        int s = src_sorted[j];
        float e = as[s] + adn;
        e = e > 0.f ? e : 0.2f * e;
        m = fmaxf(m, e);
    }
    #pragma unroll
    for (int off = 32; off; off >>= 1) m = fmaxf(m, __shfl_xor(m, off));
    // pass 2: denom
    float denom = 0.f;
    for (int j = start + lane; j < end; j += 64) {
        int s = src_sorted[j];
        float e = as[s] + adn;
        e = e > 0.f ? e : 0.2f * e;
        denom += __expf(e - m);
    }
    #pragma unroll
    for (int off = 32; off; off >>= 1) denom += __shfl_xor(denom, off);
    float inv = 1.f / denom;
    // pass 3: weighted gather
    float4 acc = make_float4(0.f, 0.f, 0.f, 0.f);
    const float4* hv = (const float4*)h;
    for (int j = start; j < end; ++j) {
        int s = src_sorted[j];
        float e = as[s] + adn;
        e = e > 0.f ? e : 0.2f * e;
        float w = __expf(e - m) * inv;
        float4 x = hv[(size_t)s * 64 + lane];
        acc.x += w * x.x; acc.y += w * x.y; acc.z += w * x.z; acc.w += w * x.w;
    }
    float4 bv = ((const float4*)bias)[lane];
    acc.x += bv.x; acc.y += bv.y; acc.z += bv.z; acc.w += bv.w;
    if (ACT) {
        acc.x = acc.x > 0.f ? acc.x : 0.01f * acc.x;
        acc.y = acc.y > 0.f ? acc.y : 0.01f * acc.y;
        acc.z = acc.z > 0.f ? acc.z : 0.01f * acc.z;
        acc.w = acc.w > 0.f ? acc.w : 0.01f * acc.w;
    }
    ((float4*)out)[(size_t)wv * 64 + lane] = acc;
}

// ---------------- graph pooling (batch is sorted) ----------------
__global__ void zero_graph_emb(float* __restrict__ graph_emb) {
    graph_emb[blockIdx.x * 256 + threadIdx.x] = 0.f;
}

// 512 blocks, 256 threads (one per feature); register-accumulate per graph
// segment, flush via atomicAdd at boundary crossings (~1-2 per block).
__global__ __launch_bounds__(256)
void pool_kernel(const float* __restrict__ node_emb, const int* __restrict__ batch,
                 float* __restrict__ graph_emb, int n) {
    int f = threadIdx.x;
    int chunk = (n + gridDim.x - 1) / gridDim.x;
    int i0 = blockIdx.x * chunk;
    int i1 = min(i0 + chunk, n);
    if (i0 >= i1) return;
    float acc = 0.f;
    int cur = batch[i0];
    for (int i = i0; i < i1; ++i) {
        int g = batch[i];                         // same addr across block: broadcast
        if (g != cur) {
            atomicAdd(&graph_emb[(size_t)cur * 256 + f], acc);
            acc = 0.f; cur = g;
        }
        acc += node_emb[(size_t)i * 256 + f];
    }
    atomicAdd(&graph_emb[(size_t)cur * 256 + f], acc);
}

extern "C" void kernel_launch(void* const* d_in, const int* in_sizes, int n_in,
                              void* d_out, int out_size, void* d_ws, size_t ws_size,
                              hipStream_t stream) {
    const float* x     = (const float*)d_in[0];
    const int* eidx    = (const int*)d_in[1];   // [2, E]: row0=src, row1=dst
    const int* batch   = (const int*)d_in[2];
    const float* W1    = (const float*)d_in[3];
    const float* a_s1  = (const float*)d_in[4];
    const float* a_d1  = (const float*)d_in[5];
    const float* b1    = (const float*)d_in[6];
    const float* W2    = (const float*)d_in[7];
    const float* a_s2  = (const float*)d_in[8];
    const float* a_d2  = (const float*)d_in[9];
    const float* b2    = (const float*)d_in[10];

    float* node_emb  = (float*)d_out;                       // [NN, 256]
    float* graph_emb = node_emb + (size_t)NN * 256;         // [NG, 256]

    char* ws = (char*)d_ws;
    float* buf_h   = (float*)ws;               ws += (size_t)NN * 256 * sizeof(float);
    float* as_buf  = (float*)ws;               ws += (size_t)NN * sizeof(float);
    float* ad_buf  = (float*)ws;               ws += (size_t)NN * sizeof(float);
    int* counts    = (int*)ws;                 ws += (size_t)NN * sizeof(int);
    int* offsets   = (int*)ws;                 ws += (size_t)(NN + 1) * sizeof(int);
    int* cursor    = (int*)ws;                 ws += (size_t)NN * sizeof(int);
    int* src_sorted = (int*)ws;                ws += (size_t)(NE + NN) * sizeof(int);

    const int* e_src = eidx;
    const int* e_dst = eidx + NE;

    dim3 gemm_grid((NN + 63) / 64, 256 / 64);
    int node_waves_blocks = (NN + 3) / 4;   // 4 waves per 256-thread block

    // ---- CSR build (shared by both layers) ----
    init_counts<<<(NN + 255) / 256, 256, 0, stream>>>(counts, NN);
    hist_kernel<<<(NE + 255) / 256, 256, 0, stream>>>(e_dst, counts, NE);
    scan_kernel<<<1, 1024, 0, stream>>>(counts, offsets, NN);
    copy_cursor<<<(NN + 255) / 256, 256, 0, stream>>>(offsets, cursor, NN);
    scatter_kernel<<<(NE + NN + 255) / 256, 256, 0, stream>>>(e_src, e_dst, cursor, src_sorted, NE, NN);

    // ---- layer 1 ----
    gemm64<<<gemm_grid, 256, 0, stream>>>(x, W1, buf_h, NN, 256, F_IN);
    attn_dots<<<node_waves_blocks, 256, 0, stream>>>(buf_h, a_s1, a_d1, as_buf, ad_buf, NN);
    agg_kernel<true><<<node_waves_blocks, 256, 0, stream>>>(buf_h, as_buf, ad_buf, offsets,
                                                            src_sorted, b1, node_emb, NN);
    // ---- layer 2 (input = activated layer-1 output living in d_out) ----
    gemm64<<<gemm_grid, 256, 0, stream>>>(node_emb, W2, buf_h, NN, 256, F_HID);
    attn_dots<<<node_waves_blocks, 256, 0, stream>>>(buf_h, a_s2, a_d2, as_buf, ad_buf, NN);
    agg_kernel<false><<<node_waves_blocks, 256, 0, stream>>>(buf_h, as_buf, ad_buf, offsets,
                                                             src_sorted, b2, node_emb, NN);
    // ---- pool ----
    zero_graph_emb<<<NG, 256, 0, stream>>>(graph_emb);
    pool_kernel<<<512, 256, 0, stream>>>(node_emb, batch, graph_emb, NN);
}

// Round 4
// 625.656 us; speedup vs baseline: 1.4770x; 1.2069x over previous
//
#include <hip/hip_runtime.h>
#include <math.h>

// Problem constants (fixed by reference)
#define NN 50000
#define NE 800000
#define F_IN 128
#define F_HID 256
#define NG 64

typedef __bf16 bf16x8 __attribute__((ext_vector_type(8)));
typedef float f32x4 __attribute__((ext_vector_type(4)));
typedef unsigned short u16x8 __attribute__((ext_vector_type(8)));   // 16 B

static __device__ __forceinline__ unsigned short f2bf(float f) {
    union { float f; unsigned u; } v; v.f = f;
    unsigned r = v.u + 0x7fff + ((v.u >> 16) & 1);   // RNE
    return (unsigned short)(r >> 16);
}

// ---------------- bf16 MFMA GEMM: C[M,256] = A[M,K] @ Wt[256,K]^T ----------
// A bf16 row-major [M,K], Wt bf16 row-major [256,K] (pre-transposed weight).
// 128x128 tile / block, 256 threads = 4 waves in 2x2, each wave 64x64 via
// 4x4 grid of 16x16x32 MFMAs. LDS stride 40 ushorts (80 B -> bank stride 20,
// 2-way over 16 rows = free).
template <int K>
__global__ __launch_bounds__(256)
void gemm_mfma(const ushort* __restrict__ A, const ushort* __restrict__ Wt,
               float* __restrict__ C, int M) {
    __shared__ ushort As[128 * 40];
    __shared__ ushort Bs[128 * 40];
    const int t = threadIdx.x;
    const int bm = blockIdx.x * 128, bn = blockIdx.y * 128;
    const int wv = t >> 6, lane = t & 63;
    const int wm = (wv & 1) * 64, wn = (wv >> 1) * 64;
    const int lrow = lane & 15, quad = lane >> 4;
    const int srow = t >> 2;            // 0..63 staging row
    const int skp = (t & 3) << 3;       // 0,8,16,24 (ushort offset, 8 each)

    f32x4 acc[4][4];
    #pragma unroll
    for (int i = 0; i < 4; ++i)
        #pragma unroll
        for (int j = 0; j < 4; ++j)
            #pragma unroll
            for (int r = 0; r < 4; ++r) acc[i][j][r] = 0.f;

    for (int k0 = 0; k0 < K; k0 += 32) {
        // global -> regs (16 B / lane each)
        int r0 = bm + srow, r1 = bm + srow + 64;
        u16x8 a0 = (u16x8)(0), a1 = (u16x8)(0);
        if (r0 < M) a0 = *(const u16x8*)(A + (size_t)r0 * K + k0 + skp);
        if (r1 < M) a1 = *(const u16x8*)(A + (size_t)r1 * K + k0 + skp);
        u16x8 b0 = *(const u16x8*)(Wt + (size_t)(bn + srow) * K + k0 + skp);
        u16x8 b1 = *(const u16x8*)(Wt + (size_t)(bn + srow + 64) * K + k0 + skp);
        __syncthreads();   // previous iter's LDS reads complete
        *(u16x8*)(As + srow * 40 + skp) = a0;
        *(u16x8*)(As + (srow + 64) * 40 + skp) = a1;
        *(u16x8*)(Bs + srow * 40 + skp) = b0;
        *(u16x8*)(Bs + (srow + 64) * 40 + skp) = b1;
        __syncthreads();
        bf16x8 af[4], bf_[4];
        #pragma unroll
        for (int i = 0; i < 4; ++i)
            af[i] = *(const bf16x8*)(As + (wm + i * 16 + lrow) * 40 + quad * 8);
        #pragma unroll
        for (int j = 0; j < 4; ++j)
            bf_[j] = *(const bf16x8*)(Bs + (wn + j * 16 + lrow) * 40 + quad * 8);
        #pragma unroll
        for (int i = 0; i < 4; ++i)
            #pragma unroll
            for (int j = 0; j < 4; ++j)
                acc[i][j] = __builtin_amdgcn_mfma_f32_16x16x32_bf16(
                    af[i], bf_[j], acc[i][j], 0, 0, 0);
    }
    // epilogue: C/D layout col=lane&15, row=quad*4+reg
    #pragma unroll
    for (int i = 0; i < 4; ++i) {
        int gm0 = bm + wm + i * 16 + quad * 4;
        #pragma unroll
        for (int j = 0; j < 4; ++j) {
            int gn = bn + wn + j * 16 + lrow;
            #pragma unroll
            for (int r = 0; r < 4; ++r)
                if (gm0 + r < M) C[(size_t)(gm0 + r) * 256 + gn] = acc[i][j][r];
        }
    }
}

// ---------------- conversions ----------------
__global__ void cvt_f32_bf16(const float* __restrict__ in, ushort* __restrict__ out, int n4) {
    int i = blockIdx.x * blockDim.x + threadIdx.x;
    if (i >= n4) return;
    float4 v = ((const float4*)in)[i];
    ushort4 o = make_ushort4(f2bf(v.x), f2bf(v.y), f2bf(v.z), f2bf(v.w));
    ((ushort4*)out)[i] = o;
}

// W[K,256] fp32 -> Wt[256,K] bf16
__global__ void cvt_wt(const float* __restrict__ W, ushort* __restrict__ Wt, int K) {
    int idx = blockIdx.x * blockDim.x + threadIdx.x;
    if (idx >= K * 256) return;
    int n = idx / K, k = idx - n * K;
    Wt[idx] = f2bf(W[(size_t)k * 256 + n]);
}

// --------- per-node attention dots: as[i]=h[i,:]·a_s, ad[i]=h[i,:]·a_d -----
__global__ __launch_bounds__(256)
void attn_dots(const float* __restrict__ h, const float* __restrict__ a_s,
               const float* __restrict__ a_d, float* __restrict__ as_out,
               float* __restrict__ ad_out, int n) {
    int wv = (int)((blockIdx.x * blockDim.x + threadIdx.x) >> 6);
    int lane = threadIdx.x & 63;
    if (wv >= n) return;
    const float4* hv = (const float4*)(h + (size_t)wv * 256);
    float4 x = hv[lane];
    float4 u = ((const float4*)a_s)[lane];
    float4 v = ((const float4*)a_d)[lane];
    float s1 = x.x * u.x + x.y * u.y + x.z * u.z + x.w * u.w;
    float s2 = x.x * v.x + x.y * v.y + x.z * v.z + x.w * v.w;
    #pragma unroll
    for (int off = 32; off; off >>= 1) {
        s1 += __shfl_xor(s1, off);
        s2 += __shfl_xor(s2, off);
    }
    if (lane == 0) { as_out[wv] = s1; ad_out[wv] = s2; }
}

// ---------------- CSR build ----------------
__global__ void init_counts(int* __restrict__ counts, int n) {
    int i = blockIdx.x * blockDim.x + threadIdx.x;
    if (i < n) counts[i] = 1;   // self-loop pre-seeded
}

__global__ void hist_kernel(const int* __restrict__ dst, int* __restrict__ counts, int E) {
    int e = blockIdx.x * blockDim.x + threadIdx.x;
    if (e < E) atomicAdd(&counts[dst[e]], 1);
}

__global__ void scan_kernel(const int* __restrict__ counts, int* __restrict__ offsets, int n) {
    __shared__ int part[1024];
    int tid = threadIdx.x;
    int chunk = (n + 1023) / 1024;
    int lo = tid * chunk;
    int hi = min(lo + chunk, n);
    int s = 0;
    for (int i = lo; i < hi; ++i) s += counts[i];
    part[tid] = s;
    __syncthreads();
    for (int d = 1; d < 1024; d <<= 1) {
        int v = (tid >= d) ? part[tid - d] : 0;
        __syncthreads();
        part[tid] += v;
        __syncthreads();
    }
    int run = (tid == 0) ? 0 : part[tid - 1];
    for (int i = lo; i < hi; ++i) { offsets[i] = run; run += counts[i]; }
    if (tid == 1023) offsets[n] = run;
}

__global__ void copy_cursor(const int* __restrict__ offsets, int* __restrict__ cursor, int n) {
    int i = blockIdx.x * blockDim.x + threadIdx.x;
    if (i < n) cursor[i] = offsets[i];
}

__global__ void scatter_kernel(const int* __restrict__ src, const int* __restrict__ dst,
                               int* __restrict__ cursor, int* __restrict__ src_sorted,
                               int E, int n) {
    int e = blockIdx.x * blockDim.x + threadIdx.x;
    if (e < E) {
        int d = dst[e];
        int pos = atomicAdd(&cursor[d], 1);
        src_sorted[pos] = src[e];
    } else if (e < E + n) {
        int i = e - E;
        int pos = atomicAdd(&cursor[i], 1);
        src_sorted[pos] = i;
    }
}

// ---------------- GAT aggregation: one wave per dst node ----------------
// BF16OUT: write bf16 (consumed only by next layer's MFMA GEMM)
template <bool ACT, bool BF16OUT>
__global__ __launch_bounds__(256)
void agg_kernel(const float* __restrict__ h, const float* __restrict__ as,
                const float* __restrict__ ad, const int* __restrict__ offsets,
                const int* __restrict__ src_sorted, const float* __restrict__ bias,
                float* __restrict__ out, ushort* __restrict__ out16, int n) {
    int wv = (int)((blockIdx.x * blockDim.x + threadIdx.x) >> 6);
    int lane = threadIdx.x & 63;
    if (wv >= n) return;
    int start = offsets[wv], end = offsets[wv + 1];
    float adn = ad[wv];
    // pass 1: max
    float m = -INFINITY;
    for (int j = start + lane; j < end; j += 64) {
        int s = src_sorted[j];
        float e = as[s] + adn;
        e = e > 0.f ? e : 0.2f * e;
        m = fmaxf(m, e);
    }
    #pragma unroll
    for (int off = 32; off; off >>= 1) m = fmaxf(m, __shfl_xor(m, off));
    // pass 2: denom
    float denom = 0.f;
    for (int j = start + lane; j < end; j += 64) {
        int s = src_sorted[j];
        float e = as[s] + adn;
        e = e > 0.f ? e : 0.2f * e;
        denom += __expf(e - m);
    }
    #pragma unroll
    for (int off = 32; off; off >>= 1) denom += __shfl_xor(denom, off);
    float inv = 1.f / denom;
    // pass 3: weighted gather
    float4 acc = make_float4(0.f, 0.f, 0.f, 0.f);
    const float4* hv = (const float4*)h;
    for (int j = start; j < end; ++j) {
        int s = src_sorted[j];
        float e = as[s] + adn;
        e = e > 0.f ? e : 0.2f * e;
        float w = __expf(e - m) * inv;
        float4 x = hv[(size_t)s * 64 + lane];
        acc.x += w * x.x; acc.y += w * x.y; acc.z += w * x.z; acc.w += w * x.w;
    }
    float4 bv = ((const float4*)bias)[lane];
    acc.x += bv.x; acc.y += bv.y; acc.z += bv.z; acc.w += bv.w;
    if (ACT) {
        acc.x = acc.x > 0.f ? acc.x : 0.01f * acc.x;
        acc.y = acc.y > 0.f ? acc.y : 0.01f * acc.y;
        acc.z = acc.z > 0.f ? acc.z : 0.01f * acc.z;
        acc.w = acc.w > 0.f ? acc.w : 0.01f * acc.w;
    }
    if (BF16OUT) {
        ushort4 o = make_ushort4(f2bf(acc.x), f2bf(acc.y), f2bf(acc.z), f2bf(acc.w));
        ((ushort4*)out16)[(size_t)wv * 64 + lane] = o;
    } else {
        ((float4*)out)[(size_t)wv * 64 + lane] = acc;
    }
}

// ---------------- graph pooling (batch is sorted) ----------------
__global__ void zero_graph_emb(float* __restrict__ graph_emb) {
    graph_emb[blockIdx.x * 256 + threadIdx.x] = 0.f;
}

__global__ __launch_bounds__(256)
void pool_kernel(const float* __restrict__ node_emb, const int* __restrict__ batch,
                 float* __restrict__ graph_emb, int n) {
    int f = threadIdx.x;
    int chunk = (n + gridDim.x - 1) / gridDim.x;
    int i0 = blockIdx.x * chunk;
    int i1 = min(i0 + chunk, n);
    if (i0 >= i1) return;
    float acc = 0.f;
    int cur = batch[i0];
    for (int i = i0; i < i1; ++i) {
        int g = batch[i];
        if (g != cur) {
            atomicAdd(&graph_emb[(size_t)cur * 256 + f], acc);
            acc = 0.f; cur = g;
        }
        acc += node_emb[(size_t)i * 256 + f];
    }
    atomicAdd(&graph_emb[(size_t)cur * 256 + f], acc);
}

static inline char* align_up(char* p, size_t a) {
    return (char*)(((uintptr_t)p + a - 1) & ~(uintptr_t)(a - 1));
}

extern "C" void kernel_launch(void* const* d_in, const int* in_sizes, int n_in,
                              void* d_out, int out_size, void* d_ws, size_t ws_size,
                              hipStream_t stream) {
    const float* x     = (const float*)d_in[0];
    const int* eidx    = (const int*)d_in[1];   // [2, E]: row0=src, row1=dst
    const int* batch   = (const int*)d_in[2];
    const float* W1    = (const float*)d_in[3];
    const float* a_s1  = (const float*)d_in[4];
    const float* a_d1  = (const float*)d_in[5];
    const float* b1    = (const float*)d_in[6];
    const float* W2    = (const float*)d_in[7];
    const float* a_s2  = (const float*)d_in[8];
    const float* a_d2  = (const float*)d_in[9];
    const float* b2    = (const float*)d_in[10];

    float* node_emb  = (float*)d_out;                       // [NN, 256]
    float* graph_emb = node_emb + (size_t)NN * 256;         // [NG, 256]

    char* ws = (char*)d_ws;
    float* buf_h = (float*)ws;   ws += (size_t)NN * 256 * sizeof(float);       // gemm out fp32
    ws = align_up(ws, 256);
    ushort* hb   = (ushort*)ws;  ws += (size_t)NN * 256 * sizeof(ushort);      // bf16 A (xb then h1b)
    ws = align_up(ws, 256);
    ushort* wt1  = (ushort*)ws;  ws += (size_t)256 * F_IN * sizeof(ushort);
    ws = align_up(ws, 256);
    ushort* wt2  = (ushort*)ws;  ws += (size_t)256 * F_HID * sizeof(ushort);
    ws = align_up(ws, 256);
    float* as_buf = (float*)ws;  ws += (size_t)NN * sizeof(float);
    float* ad_buf = (float*)ws;  ws += (size_t)NN * sizeof(float);
    int* counts   = (int*)ws;    ws += (size_t)NN * sizeof(int);
    int* offsets  = (int*)ws;    ws += (size_t)(NN + 1) * sizeof(int);
    ws = align_up(ws, 256);
    int* cursor   = (int*)ws;    ws += (size_t)NN * sizeof(int);
    int* src_sorted = (int*)ws;  ws += (size_t)(NE + NN) * sizeof(int);

    const int* e_src = eidx;
    const int* e_dst = eidx + NE;

    dim3 gemm_grid((NN + 127) / 128, 2);
    int node_waves_blocks = (NN + 3) / 4;   // 4 waves per 256-thread block

    // ---- CSR build (shared by both layers) ----
    init_counts<<<(NN + 255) / 256, 256, 0, stream>>>(counts, NN);
    hist_kernel<<<(NE + 255) / 256, 256, 0, stream>>>(e_dst, counts, NE);
    scan_kernel<<<1, 1024, 0, stream>>>(counts, offsets, NN);
    copy_cursor<<<(NN + 255) / 256, 256, 0, stream>>>(offsets, cursor, NN);
    scatter_kernel<<<(NE + NN + 255) / 256, 256, 0, stream>>>(e_src, e_dst, cursor, src_sorted, NE, NN);

    // ---- conversions ----
    cvt_f32_bf16<<<((NN * F_IN / 4) + 255) / 256, 256, 0, stream>>>(x, hb, NN * F_IN / 4);
    cvt_wt<<<(256 * F_IN + 255) / 256, 256, 0, stream>>>(W1, wt1, F_IN);
    cvt_wt<<<(256 * F_HID + 255) / 256, 256, 0, stream>>>(W2, wt2, F_HID);

    // ---- layer 1 ----
    gemm_mfma<F_IN><<<gemm_grid, 256, 0, stream>>>(hb, wt1, buf_h, NN);
    attn_dots<<<node_waves_blocks, 256, 0, stream>>>(buf_h, a_s1, a_d1, as_buf, ad_buf, NN);
    agg_kernel<true, true><<<node_waves_blocks, 256, 0, stream>>>(buf_h, as_buf, ad_buf, offsets,
                                                                  src_sorted, b1, nullptr, hb, NN);
    // ---- layer 2 (A input = bf16 h1 living in hb) ----
    gemm_mfma<F_HID><<<gemm_grid, 256, 0, stream>>>(hb, wt2, buf_h, NN);
    attn_dots<<<node_waves_blocks, 256, 0, stream>>>(buf_h, a_s2, a_d2, as_buf, ad_buf, NN);
    agg_kernel<false, false><<<node_waves_blocks, 256, 0, stream>>>(buf_h, as_buf, ad_buf, offsets,
                                                                    src_sorted, b2, node_emb, nullptr, NN);
    // ---- pool ----
    zero_graph_emb<<<NG, 256, 0, stream>>>(graph_emb);
    pool_kernel<<<512, 256, 0, stream>>>(node_emb, batch, graph_emb, NN);
}

// Round 5
// 585.136 us; speedup vs baseline: 1.5793x; 1.0692x over previous
//
#include <hip/hip_runtime.h>
#include <math.h>

// Problem constants (fixed by reference)
#define NN 50000
#define NE 800000
#define F_IN 128
#define F_HID 256
#define NG 64

typedef __bf16 bf16x8 __attribute__((ext_vector_type(8)));
typedef float f32x4 __attribute__((ext_vector_type(4)));
typedef unsigned short u16x8 __attribute__((ext_vector_type(8)));   // 16 B

static __device__ __forceinline__ unsigned short f2bf(float f) {
    union { float f; unsigned u; } v; v.f = f;
    unsigned r = v.u + 0x7fff + ((v.u >> 16) & 1);   // RNE
    return (unsigned short)(r >> 16);
}
static __device__ __forceinline__ float bf2f(unsigned short u) {
    union { unsigned u; float f; } v; v.u = ((unsigned)u) << 16;
    return v.f;
}

// ---------------- bf16 MFMA GEMM: C16[M,256] = A[M,K] @ Wt[256,K]^T --------
// A bf16 row-major [M,K], Wt bf16 row-major [256,K] (pre-transposed weight).
// 128x128 tile / block, 4 waves in 2x2, each wave 64x64 via 4x4 of
// 16x16x32 MFMAs. Output written as bf16 (consumed by attn_dots + gather).
template <int K>
__global__ __launch_bounds__(256)
void gemm_mfma(const ushort* __restrict__ A, const ushort* __restrict__ Wt,
               ushort* __restrict__ C16, int M) {
    __shared__ ushort As[128 * 40];
    __shared__ ushort Bs[128 * 40];
    const int t = threadIdx.x;
    const int bm = blockIdx.x * 128, bn = blockIdx.y * 128;
    const int wv = t >> 6, lane = t & 63;
    const int wm = (wv & 1) * 64, wn = (wv >> 1) * 64;
    const int lrow = lane & 15, quad = lane >> 4;
    const int srow = t >> 2;            // 0..63 staging row
    const int skp = (t & 3) << 3;       // 0,8,16,24 (ushort offset, 8 each)

    f32x4 acc[4][4];
    #pragma unroll
    for (int i = 0; i < 4; ++i)
        #pragma unroll
        for (int j = 0; j < 4; ++j)
            #pragma unroll
            for (int r = 0; r < 4; ++r) acc[i][j][r] = 0.f;

    for (int k0 = 0; k0 < K; k0 += 32) {
        int r0 = bm + srow, r1 = bm + srow + 64;
        u16x8 a0 = (u16x8)(0), a1 = (u16x8)(0);
        if (r0 < M) a0 = *(const u16x8*)(A + (size_t)r0 * K + k0 + skp);
        if (r1 < M) a1 = *(const u16x8*)(A + (size_t)r1 * K + k0 + skp);
        u16x8 b0 = *(const u16x8*)(Wt + (size_t)(bn + srow) * K + k0 + skp);
        u16x8 b1 = *(const u16x8*)(Wt + (size_t)(bn + srow + 64) * K + k0 + skp);
        __syncthreads();
        *(u16x8*)(As + srow * 40 + skp) = a0;
        *(u16x8*)(As + (srow + 64) * 40 + skp) = a1;
        *(u16x8*)(Bs + srow * 40 + skp) = b0;
        *(u16x8*)(Bs + (srow + 64) * 40 + skp) = b1;
        __syncthreads();
        bf16x8 af[4], bf_[4];
        #pragma unroll
        for (int i = 0; i < 4; ++i)
            af[i] = *(const bf16x8*)(As + (wm + i * 16 + lrow) * 40 + quad * 8);
        #pragma unroll
        for (int j = 0; j < 4; ++j)
            bf_[j] = *(const bf16x8*)(Bs + (wn + j * 16 + lrow) * 40 + quad * 8);
        #pragma unroll
        for (int i = 0; i < 4; ++i)
            #pragma unroll
            for (int j = 0; j < 4; ++j)
                acc[i][j] = __builtin_amdgcn_mfma_f32_16x16x32_bf16(
                    af[i], bf_[j], acc[i][j], 0, 0, 0);
    }
    // epilogue: C/D layout col=lane&15, row=quad*4+reg -> bf16 store
    #pragma unroll
    for (int i = 0; i < 4; ++i) {
        int gm0 = bm + wm + i * 16 + quad * 4;
        #pragma unroll
        for (int j = 0; j < 4; ++j) {
            int gn = bn + wn + j * 16 + lrow;
            #pragma unroll
            for (int r = 0; r < 4; ++r)
                if (gm0 + r < M) C16[(size_t)(gm0 + r) * 256 + gn] = f2bf(acc[i][j][r]);
        }
    }
}

// ---------------- conversions ----------------
__global__ void cvt_f32_bf16(const float* __restrict__ in, ushort* __restrict__ out, int n4) {
    int i = blockIdx.x * blockDim.x + threadIdx.x;
    if (i >= n4) return;
    float4 v = ((const float4*)in)[i];
    ushort4 o = make_ushort4(f2bf(v.x), f2bf(v.y), f2bf(v.z), f2bf(v.w));
    ((ushort4*)out)[i] = o;
}

// W[K,256] fp32 -> Wt[256,K] bf16
__global__ void cvt_wt(const float* __restrict__ W, ushort* __restrict__ Wt, int K) {
    int idx = blockIdx.x * blockDim.x + threadIdx.x;
    if (idx >= K * 256) return;
    int n = idx / K, k = idx - n * K;
    Wt[idx] = f2bf(W[(size_t)k * 256 + n]);
}

// --------- per-node attention dots (bf16 h): as[i]=h[i,:]·a_s, ad=·a_d -----
__global__ __launch_bounds__(256)
void attn_dots(const ushort* __restrict__ h, const float* __restrict__ a_s,
               const float* __restrict__ a_d, float* __restrict__ as_out,
               float* __restrict__ ad_out, int n) {
    int wv = (int)((blockIdx.x * blockDim.x + threadIdx.x) >> 6);
    int lane = threadIdx.x & 63;
    if (wv >= n) return;
    ushort4 hx = ((const ushort4*)(h + (size_t)wv * 256))[lane];
    float4 u = ((const float4*)a_s)[lane];
    float4 v = ((const float4*)a_d)[lane];
    float x0 = bf2f(hx.x), x1 = bf2f(hx.y), x2 = bf2f(hx.z), x3 = bf2f(hx.w);
    float s1 = x0 * u.x + x1 * u.y + x2 * u.z + x3 * u.w;
    float s2 = x0 * v.x + x1 * v.y + x2 * v.z + x3 * v.w;
    #pragma unroll
    for (int off = 32; off; off >>= 1) {
        s1 += __shfl_xor(s1, off);
        s2 += __shfl_xor(s2, off);
    }
    if (lane == 0) { as_out[wv] = s1; ad_out[wv] = s2; }
}

// ---------------- CSR build ----------------
__global__ void init_counts(int* __restrict__ counts, int n) {
    int i = blockIdx.x * blockDim.x + threadIdx.x;
    if (i < n) counts[i] = 1;   // self-loop pre-seeded
}

__global__ void hist_kernel(const int* __restrict__ dst, int* __restrict__ counts, int E) {
    int e = blockIdx.x * blockDim.x + threadIdx.x;
    if (e < E) atomicAdd(&counts[dst[e]], 1);
}

__global__ void scan_kernel(const int* __restrict__ counts, int* __restrict__ offsets, int n) {
    __shared__ int part[1024];
    int tid = threadIdx.x;
    int chunk = (n + 1023) / 1024;
    int lo = tid * chunk;
    int hi = min(lo + chunk, n);
    int s = 0;
    for (int i = lo; i < hi; ++i) s += counts[i];
    part[tid] = s;
    __syncthreads();
    for (int d = 1; d < 1024; d <<= 1) {
        int v = (tid >= d) ? part[tid - d] : 0;
        __syncthreads();
        part[tid] += v;
        __syncthreads();
    }
    int run = (tid == 0) ? 0 : part[tid - 1];
    for (int i = lo; i < hi; ++i) { offsets[i] = run; run += counts[i]; }
    if (tid == 1023) offsets[n] = run;
}

__global__ void copy_cursor(const int* __restrict__ offsets, int* __restrict__ cursor, int n) {
    int i = blockIdx.x * blockDim.x + threadIdx.x;
    if (i < n) cursor[i] = offsets[i];
}

__global__ void scatter_kernel(const int* __restrict__ src, const int* __restrict__ dst,
                               int* __restrict__ cursor, int* __restrict__ src_sorted,
                               int E, int n) {
    int e = blockIdx.x * blockDim.x + threadIdx.x;
    if (e < E) {
        int d = dst[e];
        int pos = atomicAdd(&cursor[d], 1);
        src_sorted[pos] = src[e];
    } else if (e < E + n) {
        int i = e - E;
        int pos = atomicAdd(&cursor[i], 1);
        src_sorted[pos] = i;
    }
}

// ---------------- GAT aggregation: one wave per dst node ----------------
// h is bf16 [n,256]; gather 8 B/lane; accumulate fp32.
// BF16OUT: write bf16 (consumed only by next layer's MFMA GEMM)
template <bool ACT, bool BF16OUT>
__global__ __launch_bounds__(256)
void agg_kernel(const ushort* __restrict__ h, const float* __restrict__ as,
                const float* __restrict__ ad, const int* __restrict__ offsets,
                const int* __restrict__ src_sorted, const float* __restrict__ bias,
                float* __restrict__ out, ushort* __restrict__ out16, int n) {
    int wv = (int)((blockIdx.x * blockDim.x + threadIdx.x) >> 6);
    int lane = threadIdx.x & 63;
    if (wv >= n) return;
    int start = offsets[wv], end = offsets[wv + 1];
    float adn = ad[wv];
    // pass 1: max
    float m = -INFINITY;
    for (int j = start + lane; j < end; j += 64) {
        int s = src_sorted[j];
        float e = as[s] + adn;
        e = e > 0.f ? e : 0.2f * e;
        m = fmaxf(m, e);
    }
    #pragma unroll
    for (int off = 32; off; off >>= 1) m = fmaxf(m, __shfl_xor(m, off));
    // pass 2: denom
    float denom = 0.f;
    for (int j = start + lane; j < end; j += 64) {
        int s = src_sorted[j];
        float e = as[s] + adn;
        e = e > 0.f ? e : 0.2f * e;
        denom += __expf(e - m);
    }
    #pragma unroll
    for (int off = 32; off; off >>= 1) denom += __shfl_xor(denom, off);
    float inv = 1.f / denom;
    // pass 3: weighted bf16 gather
    float4 acc = make_float4(0.f, 0.f, 0.f, 0.f);
    const ushort4* hv = (const ushort4*)h;
    for (int j = start; j < end; ++j) {
        int s = src_sorted[j];
        float e = as[s] + adn;
        e = e > 0.f ? e : 0.2f * e;
        float w = __expf(e - m) * inv;
        ushort4 x = hv[(size_t)s * 64 + lane];
        acc.x += w * bf2f(x.x); acc.y += w * bf2f(x.y);
        acc.z += w * bf2f(x.z); acc.w += w * bf2f(x.w);
    }
    float4 bv = ((const float4*)bias)[lane];
    acc.x += bv.x; acc.y += bv.y; acc.z += bv.z; acc.w += bv.w;
    if (ACT) {
        acc.x = acc.x > 0.f ? acc.x : 0.01f * acc.x;
        acc.y = acc.y > 0.f ? acc.y : 0.01f * acc.y;
        acc.z = acc.z > 0.f ? acc.z : 0.01f * acc.z;
        acc.w = acc.w > 0.f ? acc.w : 0.01f * acc.w;
    }
    if (BF16OUT) {
        ushort4 o = make_ushort4(f2bf(acc.x), f2bf(acc.y), f2bf(acc.z), f2bf(acc.w));
        ((ushort4*)out16)[(size_t)wv * 64 + lane] = o;
    } else {
        ((float4*)out)[(size_t)wv * 64 + lane] = acc;
    }
}

// ---------------- graph pooling (batch is sorted) ----------------
__global__ void zero_graph_emb(float* __restrict__ graph_emb) {
    graph_emb[blockIdx.x * 256 + threadIdx.x] = 0.f;
}

__global__ __launch_bounds__(256)
void pool_kernel(const float* __restrict__ node_emb, const int* __restrict__ batch,
                 float* __restrict__ graph_emb, int n) {
    int f = threadIdx.x;
    int chunk = (n + gridDim.x - 1) / gridDim.x;
    int i0 = blockIdx.x * chunk;
    int i1 = min(i0 + chunk, n);
    if (i0 >= i1) return;
    float acc = 0.f;
    int cur = batch[i0];
    for (int i = i0; i < i1; ++i) {
        int g = batch[i];
        if (g != cur) {
            atomicAdd(&graph_emb[(size_t)cur * 256 + f], acc);
            acc = 0.f; cur = g;
        }
        acc += node_emb[(size_t)i * 256 + f];
    }
    atomicAdd(&graph_emb[(size_t)cur * 256 + f], acc);
}

static inline char* align_up(char* p, size_t a) {
    return (char*)(((uintptr_t)p + a - 1) & ~(uintptr_t)(a - 1));
}

extern "C" void kernel_launch(void* const* d_in, const int* in_sizes, int n_in,
                              void* d_out, int out_size, void* d_ws, size_t ws_size,
                              hipStream_t stream) {
    const float* x     = (const float*)d_in[0];
    const int* eidx    = (const int*)d_in[1];   // [2, E]: row0=src, row1=dst
    const int* batch   = (const int*)d_in[2];
    const float* W1    = (const float*)d_in[3];
    const float* a_s1  = (const float*)d_in[4];
    const float* a_d1  = (const float*)d_in[5];
    const float* b1    = (const float*)d_in[6];
    const float* W2    = (const float*)d_in[7];
    const float* a_s2  = (const float*)d_in[8];
    const float* a_d2  = (const float*)d_in[9];
    const float* b2    = (const float*)d_in[10];

    float* node_emb  = (float*)d_out;                       // [NN, 256]
    float* graph_emb = node_emb + (size_t)NN * 256;         // [NG, 256]

    char* ws = (char*)d_ws;
    ushort* h16  = (ushort*)ws;  ws += (size_t)NN * 256 * sizeof(ushort);  // gemm out (bf16)
    ws = align_up(ws, 256);
    ushort* z16  = (ushort*)ws;  ws += (size_t)NN * 256 * sizeof(ushort);  // xb, then agg1 out
    ws = align_up(ws, 256);
    ushort* wt1  = (ushort*)ws;  ws += (size_t)256 * F_IN * sizeof(ushort);
    ws = align_up(ws, 256);
    ushort* wt2  = (ushort*)ws;  ws += (size_t)256 * F_HID * sizeof(ushort);
    ws = align_up(ws, 256);
    float* as_buf = (float*)ws;  ws += (size_t)NN * sizeof(float);
    float* ad_buf = (float*)ws;  ws += (size_t)NN * sizeof(float);
    int* counts   = (int*)ws;    ws += (size_t)NN * sizeof(int);
    int* offsets  = (int*)ws;    ws += (size_t)(NN + 1) * sizeof(int);
    ws = align_up(ws, 256);
    int* cursor   = (int*)ws;    ws += (size_t)NN * sizeof(int);
    int* src_sorted = (int*)ws;  ws += (size_t)(NE + NN) * sizeof(int);

    const int* e_src = eidx;
    const int* e_dst = eidx + NE;

    dim3 gemm_grid((NN + 127) / 128, 2);
    int node_waves_blocks = (NN + 3) / 4;   // 4 waves per 256-thread block

    // ---- CSR build (shared by both layers) ----
    init_counts<<<(NN + 255) / 256, 256, 0, stream>>>(counts, NN);
    hist_kernel<<<(NE + 255) / 256, 256, 0, stream>>>(e_dst, counts, NE);
    scan_kernel<<<1, 1024, 0, stream>>>(counts, offsets, NN);
    copy_cursor<<<(NN + 255) / 256, 256, 0, stream>>>(offsets, cursor, NN);
    scatter_kernel<<<(NE + NN + 255) / 256, 256, 0, stream>>>(e_src, e_dst, cursor, src_sorted, NE, NN);

    // ---- conversions (xb lives in z16: gemm1 input) ----
    cvt_f32_bf16<<<((NN * F_IN / 4) + 255) / 256, 256, 0, stream>>>(x, z16, NN * F_IN / 4);
    cvt_wt<<<(256 * F_IN + 255) / 256, 256, 0, stream>>>(W1, wt1, F_IN);
    cvt_wt<<<(256 * F_HID + 255) / 256, 256, 0, stream>>>(W2, wt2, F_HID);

    // ---- layer 1 ----
    gemm_mfma<F_IN><<<gemm_grid, 256, 0, stream>>>(z16, wt1, h16, NN);
    attn_dots<<<node_waves_blocks, 256, 0, stream>>>(h16, a_s1, a_d1, as_buf, ad_buf, NN);
    agg_kernel<true, true><<<node_waves_blocks, 256, 0, stream>>>(h16, as_buf, ad_buf, offsets,
                                                                  src_sorted, b1, nullptr, z16, NN);
    // ---- layer 2 ----
    gemm_mfma<F_HID><<<gemm_grid, 256, 0, stream>>>(z16, wt2, h16, NN);
    attn_dots<<<node_waves_blocks, 256, 0, stream>>>(h16, a_s2, a_d2, as_buf, ad_buf, NN);
    agg_kernel<false, false><<<node_waves_blocks, 256, 0, stream>>>(h16, as_buf, ad_buf, offsets,
                                                                    src_sorted, b2, node_emb, nullptr, NN);
    // ---- pool ----
    zero_graph_emb<<<NG, 256, 0, stream>>>(graph_emb);
    pool_kernel<<<512, 256, 0, stream>>>(node_emb, batch, graph_emb, NN);
}

// Round 6
// 491.647 us; speedup vs baseline: 1.8796x; 1.1902x over previous
//
#include <hip/hip_runtime.h>
#include <math.h>

// Problem constants (fixed by reference)
#define NN 50000
#define NE 800000
#define F_IN 128
#define F_HID 256
#define NG 64

typedef __bf16 bf16x8 __attribute__((ext_vector_type(8)));
typedef float f32x4 __attribute__((ext_vector_type(4)));
typedef unsigned short u16x8 __attribute__((ext_vector_type(8)));   // 16 B

static __device__ __forceinline__ unsigned short f2bf(float f) {
    union { float f; unsigned u; } v; v.f = f;
    unsigned r = v.u + 0x7fff + ((v.u >> 16) & 1);   // RNE
    return (unsigned short)(r >> 16);
}
static __device__ __forceinline__ float bf2f(unsigned short u) {
    union { unsigned u; float f; } v; v.u = ((unsigned)u) << 16;
    return v.f;
}

// ---------------- bf16 MFMA GEMM: C16[M,256] = A[M,K] @ Wt[256,K]^T --------
template <int K>
__global__ __launch_bounds__(256)
void gemm_mfma(const ushort* __restrict__ A, const ushort* __restrict__ Wt,
               ushort* __restrict__ C16, int M) {
    __shared__ ushort As[128 * 40];
    __shared__ ushort Bs[128 * 40];
    const int t = threadIdx.x;
    const int bm = blockIdx.x * 128, bn = blockIdx.y * 128;
    const int wv = t >> 6, lane = t & 63;
    const int wm = (wv & 1) * 64, wn = (wv >> 1) * 64;
    const int lrow = lane & 15, quad = lane >> 4;
    const int srow = t >> 2;            // 0..63 staging row
    const int skp = (t & 3) << 3;       // 0,8,16,24 (ushort offset, 8 each)

    f32x4 acc[4][4];
    #pragma unroll
    for (int i = 0; i < 4; ++i)
        #pragma unroll
        for (int j = 0; j < 4; ++j)
            #pragma unroll
            for (int r = 0; r < 4; ++r) acc[i][j][r] = 0.f;

    for (int k0 = 0; k0 < K; k0 += 32) {
        int r0 = bm + srow, r1 = bm + srow + 64;
        u16x8 a0 = (u16x8)(0), a1 = (u16x8)(0);
        if (r0 < M) a0 = *(const u16x8*)(A + (size_t)r0 * K + k0 + skp);
        if (r1 < M) a1 = *(const u16x8*)(A + (size_t)r1 * K + k0 + skp);
        u16x8 b0 = *(const u16x8*)(Wt + (size_t)(bn + srow) * K + k0 + skp);
        u16x8 b1 = *(const u16x8*)(Wt + (size_t)(bn + srow + 64) * K + k0 + skp);
        __syncthreads();
        *(u16x8*)(As + srow * 40 + skp) = a0;
        *(u16x8*)(As + (srow + 64) * 40 + skp) = a1;
        *(u16x8*)(Bs + srow * 40 + skp) = b0;
        *(u16x8*)(Bs + (srow + 64) * 40 + skp) = b1;
        __syncthreads();
        bf16x8 af[4], bf_[4];
        #pragma unroll
        for (int i = 0; i < 4; ++i)
            af[i] = *(const bf16x8*)(As + (wm + i * 16 + lrow) * 40 + quad * 8);
        #pragma unroll
        for (int j = 0; j < 4; ++j)
            bf_[j] = *(const bf16x8*)(Bs + (wn + j * 16 + lrow) * 40 + quad * 8);
        #pragma unroll
        for (int i = 0; i < 4; ++i)
            #pragma unroll
            for (int j = 0; j < 4; ++j)
                acc[i][j] = __builtin_amdgcn_mfma_f32_16x16x32_bf16(
                    af[i], bf_[j], acc[i][j], 0, 0, 0);
    }
    // epilogue: C/D layout col=lane&15, row=quad*4+reg -> bf16 store
    #pragma unroll
    for (int i = 0; i < 4; ++i) {
        int gm0 = bm + wm + i * 16 + quad * 4;
        #pragma unroll
        for (int j = 0; j < 4; ++j) {
            int gn = bn + wn + j * 16 + lrow;
            #pragma unroll
            for (int r = 0; r < 4; ++r)
                if (gm0 + r < M) C16[(size_t)(gm0 + r) * 256 + gn] = f2bf(acc[i][j][r]);
        }
    }
}

// ---------------- conversions ----------------
__global__ void cvt_f32_bf16(const float* __restrict__ in, ushort* __restrict__ out, int n4) {
    int i = blockIdx.x * blockDim.x + threadIdx.x;
    if (i >= n4) return;
    float4 v = ((const float4*)in)[i];
    ushort4 o = make_ushort4(f2bf(v.x), f2bf(v.y), f2bf(v.z), f2bf(v.w));
    ((ushort4*)out)[i] = o;
}

// W[K,256] fp32 -> Wt[256,K] bf16
__global__ void cvt_wt(const float* __restrict__ W, ushort* __restrict__ Wt, int K) {
    int idx = blockIdx.x * blockDim.x + threadIdx.x;
    if (idx >= K * 256) return;
    int n = idx / K, k = idx - n * K;
    Wt[idx] = f2bf(W[(size_t)k * 256 + n]);
}

// --------- per-node attention dots (bf16 h): as[i]=h[i,:]·a_s, ad=·a_d -----
__global__ __launch_bounds__(256)
void attn_dots(const ushort* __restrict__ h, const float* __restrict__ a_s,
               const float* __restrict__ a_d, float* __restrict__ as_out,
               float* __restrict__ ad_out, int n) {
    int wv = (int)((blockIdx.x * blockDim.x + threadIdx.x) >> 6);
    int lane = threadIdx.x & 63;
    if (wv >= n) return;
    ushort4 hx = ((const ushort4*)(h + (size_t)wv * 256))[lane];
    float4 u = ((const float4*)a_s)[lane];
    float4 v = ((const float4*)a_d)[lane];
    float x0 = bf2f(hx.x), x1 = bf2f(hx.y), x2 = bf2f(hx.z), x3 = bf2f(hx.w);
    float s1 = x0 * u.x + x1 * u.y + x2 * u.z + x3 * u.w;
    float s2 = x0 * v.x + x1 * v.y + x2 * v.z + x3 * v.w;
    #pragma unroll
    for (int off = 32; off; off >>= 1) {
        s1 += __shfl_xor(s1, off);
        s2 += __shfl_xor(s2, off);
    }
    if (lane == 0) { as_out[wv] = s1; ad_out[wv] = s2; }
}

// ---------------- CSR build ----------------
__global__ void init_counts(int* __restrict__ counts, int n) {
    int i = blockIdx.x * blockDim.x + threadIdx.x;
    if (i < n) counts[i] = 1;   // self-loop pre-seeded
}

__global__ void hist_kernel(const int* __restrict__ dst, int* __restrict__ counts, int E) {
    int e = blockIdx.x * blockDim.x + threadIdx.x;
    if (e < E) atomicAdd(&counts[dst[e]], 1);
}

__global__ void scan_kernel(const int* __restrict__ counts, int* __restrict__ offsets, int n) {
    __shared__ int part[1024];
    int tid = threadIdx.x;
    int chunk = (n + 1023) / 1024;
    int lo = tid * chunk;
    int hi = min(lo + chunk, n);
    int s = 0;
    for (int i = lo; i < hi; ++i) s += counts[i];
    part[tid] = s;
    __syncthreads();
    for (int d = 1; d < 1024; d <<= 1) {
        int v = (tid >= d) ? part[tid - d] : 0;
        __syncthreads();
        part[tid] += v;
        __syncthreads();
    }
    int run = (tid == 0) ? 0 : part[tid - 1];
    for (int i = lo; i < hi; ++i) { offsets[i] = run; run += counts[i]; }
    if (tid == 1023) offsets[n] = run;
}

__global__ void copy_cursor(const int* __restrict__ offsets, int* __restrict__ cursor, int n) {
    int i = blockIdx.x * blockDim.x + threadIdx.x;
    if (i < n) cursor[i] = offsets[i];
}

__global__ void scatter_kernel(const int* __restrict__ src, const int* __restrict__ dst,
                               int* __restrict__ cursor, int* __restrict__ src_sorted,
                               int E, int n) {
    int e = blockIdx.x * blockDim.x + threadIdx.x;
    if (e < E) {
        int d = dst[e];
        int pos = atomicAdd(&cursor[d], 1);
        src_sorted[pos] = src[e];
    } else if (e < E + n) {
        int i = e - E;
        int pos = atomicAdd(&cursor[i], 1);
        src_sorted[pos] = i;
    }
}

// ---------------- GAT aggregation v2: one wave per dst node ----------------
// Register-resident attention state: src id + logit per lane (deg<=64 fast
// path, essentially always). Pass 3: 2 edges/iter, half-wave 16 B gathers,
// w and s via shuffle (no memory ops besides the row gather).
template <bool ACT, bool BF16OUT>
__global__ __launch_bounds__(256)
void agg_kernel(const ushort* __restrict__ h, const float* __restrict__ as,
                const float* __restrict__ ad, const int* __restrict__ offsets,
                const int* __restrict__ src_sorted, const float* __restrict__ bias,
                float* __restrict__ out, ushort* __restrict__ out16, int n) {
    int wv = (int)((blockIdx.x * blockDim.x + threadIdx.x) >> 6);
    int lane = threadIdx.x & 63;
    if (wv >= n) return;
    int start = offsets[wv], end = offsets[wv + 1];
    int deg = end - start;
    float adn = ad[wv];

    // per-lane edge state for first min(deg,64) edges
    int s_lane = 0;
    float e_lane = -INFINITY;
    if (lane < deg) {
        s_lane = src_sorted[start + lane];
        float e = as[s_lane] + adn;
        e_lane = e > 0.f ? e : 0.2f * e;
    }
    float m = e_lane;
    for (int j = start + 64 + lane; j < end; j += 64) {   // deg>64 tail (rare)
        int s = src_sorted[j];
        float e = as[s] + adn;
        e = e > 0.f ? e : 0.2f * e;
        m = fmaxf(m, e);
    }
    #pragma unroll
    for (int off = 32; off; off >>= 1) m = fmaxf(m, __shfl_xor(m, off));
    float p_lane = __expf(e_lane - m);                    // 0 for inactive lanes
    float denom = p_lane;
    for (int j = start + 64 + lane; j < end; j += 64) {   // rare
        int s = src_sorted[j];
        float e = as[s] + adn;
        e = e > 0.f ? e : 0.2f * e;
        denom += __expf(e - m);
    }
    #pragma unroll
    for (int off = 32; off; off >>= 1) denom += __shfl_xor(denom, off);
    float inv = 1.f / denom;

    // pass 3: lanes 0-31 -> even edge, lanes 32-63 -> odd edge; 16 B/lane
    const int half = lane >> 5;
    const int hl = lane & 31;
    float acc[8] = {0.f, 0.f, 0.f, 0.f, 0.f, 0.f, 0.f, 0.f};
    for (int j0 = 0; j0 < deg; j0 += 2) {
        int myj = j0 + half;
        int src_idx = min(myj, 63);
        float w = __shfl(p_lane, src_idx) * inv;
        int s = __shfl(s_lane, src_idx);
        bool valid = myj < deg;
        if (myj >= 64 && valid) {                         // rare tail
            s = src_sorted[start + myj];
            float e = as[s] + adn;
            e = e > 0.f ? e : 0.2f * e;
            w = __expf(e - m) * inv;
        }
        if (valid) {
            u16x8 row = *(const u16x8*)(h + (size_t)s * 256 + hl * 8);
            #pragma unroll
            for (int k = 0; k < 8; ++k) acc[k] += w * bf2f(row[k]);
        }
    }
    #pragma unroll
    for (int k = 0; k < 8; ++k) acc[k] += __shfl_xor(acc[k], 32);
    if (half == 0) {
        const float4* b4 = (const float4*)bias;
        float4 b0 = b4[hl * 2], b1 = b4[hl * 2 + 1];
        float v[8];
        v[0] = acc[0] + b0.x; v[1] = acc[1] + b0.y; v[2] = acc[2] + b0.z; v[3] = acc[3] + b0.w;
        v[4] = acc[4] + b1.x; v[5] = acc[5] + b1.y; v[6] = acc[6] + b1.z; v[7] = acc[7] + b1.w;
        if (ACT) {
            #pragma unroll
            for (int k = 0; k < 8; ++k) v[k] = v[k] > 0.f ? v[k] : 0.01f * v[k];
        }
        if (BF16OUT) {
            u16x8 o;
            #pragma unroll
            for (int k = 0; k < 8; ++k) o[k] = f2bf(v[k]);
            *(u16x8*)(out16 + (size_t)wv * 256 + hl * 8) = o;
        } else {
            float4 o0 = make_float4(v[0], v[1], v[2], v[3]);
            float4 o1 = make_float4(v[4], v[5], v[6], v[7]);
            float4* op = (float4*)(out + (size_t)wv * 256);
            op[hl * 2] = o0;
            op[hl * 2 + 1] = o1;
        }
    }
}

// ---------------- graph pooling (batch is sorted) ----------------
__global__ void zero_graph_emb(float* __restrict__ graph_emb) {
    graph_emb[blockIdx.x * 256 + threadIdx.x] = 0.f;
}

__global__ __launch_bounds__(256)
void pool_kernel(const float* __restrict__ node_emb, const int* __restrict__ batch,
                 float* __restrict__ graph_emb, int n) {
    int f = threadIdx.x;
    int chunk = (n + gridDim.x - 1) / gridDim.x;
    int i0 = blockIdx.x * chunk;
    int i1 = min(i0 + chunk, n);
    if (i0 >= i1) return;
    float acc = 0.f;
    int cur = batch[i0];
    for (int i = i0; i < i1; ++i) {
        int g = batch[i];
        if (g != cur) {
            atomicAdd(&graph_emb[(size_t)cur * 256 + f], acc);
            acc = 0.f; cur = g;
        }
        acc += node_emb[(size_t)i * 256 + f];
    }
    atomicAdd(&graph_emb[(size_t)cur * 256 + f], acc);
}

static inline char* align_up(char* p, size_t a) {
    return (char*)(((uintptr_t)p + a - 1) & ~(uintptr_t)(a - 1));
}

extern "C" void kernel_launch(void* const* d_in, const int* in_sizes, int n_in,
                              void* d_out, int out_size, void* d_ws, size_t ws_size,
                              hipStream_t stream) {
    const float* x     = (const float*)d_in[0];
    const int* eidx    = (const int*)d_in[1];   // [2, E]: row0=src, row1=dst
    const int* batch   = (const int*)d_in[2];
    const float* W1    = (const float*)d_in[3];
    const float* a_s1  = (const float*)d_in[4];
    const float* a_d1  = (const float*)d_in[5];
    const float* b1    = (const float*)d_in[6];
    const float* W2    = (const float*)d_in[7];
    const float* a_s2  = (const float*)d_in[8];
    const float* a_d2  = (const float*)d_in[9];
    const float* b2    = (const float*)d_in[10];

    float* node_emb  = (float*)d_out;                       // [NN, 256]
    float* graph_emb = node_emb + (size_t)NN * 256;         // [NG, 256]

    char* ws = (char*)d_ws;
    ushort* h16  = (ushort*)ws;  ws += (size_t)NN * 256 * sizeof(ushort);  // gemm out (bf16)
    ws = align_up(ws, 256);
    ushort* z16  = (ushort*)ws;  ws += (size_t)NN * 256 * sizeof(ushort);  // xb, then agg1 out
    ws = align_up(ws, 256);
    ushort* wt1  = (ushort*)ws;  ws += (size_t)256 * F_IN * sizeof(ushort);
    ws = align_up(ws, 256);
    ushort* wt2  = (ushort*)ws;  ws += (size_t)256 * F_HID * sizeof(ushort);
    ws = align_up(ws, 256);
    float* as_buf = (float*)ws;  ws += (size_t)NN * sizeof(float);
    float* ad_buf = (float*)ws;  ws += (size_t)NN * sizeof(float);
    int* counts   = (int*)ws;    ws += (size_t)NN * sizeof(int);
    int* offsets  = (int*)ws;    ws += (size_t)(NN + 1) * sizeof(int);
    ws = align_up(ws, 256);
    int* cursor   = (int*)ws;    ws += (size_t)NN * sizeof(int);
    int* src_sorted = (int*)ws;  ws += (size_t)(NE + NN) * sizeof(int);

    const int* e_src = eidx;
    const int* e_dst = eidx + NE;

    dim3 gemm_grid((NN + 127) / 128, 2);
    int node_waves_blocks = (NN + 3) / 4;   // 4 waves per 256-thread block

    // ---- CSR build (shared by both layers) ----
    init_counts<<<(NN + 255) / 256, 256, 0, stream>>>(counts, NN);
    hist_kernel<<<(NE + 255) / 256, 256, 0, stream>>>(e_dst, counts, NE);
    scan_kernel<<<1, 1024, 0, stream>>>(counts, offsets, NN);
    copy_cursor<<<(NN + 255) / 256, 256, 0, stream>>>(offsets, cursor, NN);
    scatter_kernel<<<(NE + NN + 255) / 256, 256, 0, stream>>>(e_src, e_dst, cursor, src_sorted, NE, NN);

    // ---- conversions (xb lives in z16: gemm1 input) ----
    cvt_f32_bf16<<<((NN * F_IN / 4) + 255) / 256, 256, 0, stream>>>(x, z16, NN * F_IN / 4);
    cvt_wt<<<(256 * F_IN + 255) / 256, 256, 0, stream>>>(W1, wt1, F_IN);
    cvt_wt<<<(256 * F_HID + 255) / 256, 256, 0, stream>>>(W2, wt2, F_HID);

    // ---- layer 1 ----
    gemm_mfma<F_IN><<<gemm_grid, 256, 0, stream>>>(z16, wt1, h16, NN);
    attn_dots<<<node_waves_blocks, 256, 0, stream>>>(h16, a_s1, a_d1, as_buf, ad_buf, NN);
    agg_kernel<true, true><<<node_waves_blocks, 256, 0, stream>>>(h16, as_buf, ad_buf, offsets,
                                                                  src_sorted, b1, nullptr, z16, NN);
    // ---- layer 2 ----
    gemm_mfma<F_HID><<<gemm_grid, 256, 0, stream>>>(z16, wt2, h16, NN);
    attn_dots<<<node_waves_blocks, 256, 0, stream>>>(h16, a_s2, a_d2, as_buf, ad_buf, NN);
    agg_kernel<false, false><<<node_waves_blocks, 256, 0, stream>>>(h16, as_buf, ad_buf, offsets,
                                                                    src_sorted, b2, node_emb, nullptr, NN);
    // ---- pool ----
    zero_graph_emb<<<NG, 256, 0, stream>>>(graph_emb);
    pool_kernel<<<512, 256, 0, stream>>>(node_emb, batch, graph_emb, NN);
}

// Round 7
// 424.025 us; speedup vs baseline: 2.1794x; 1.1595x over previous
//
#include <hip/hip_runtime.h>
#include <math.h>

// Problem constants (fixed by reference)
#define NN 50000
#define NE 800000
#define F_IN 128
#define F_HID 256
#define NG 64
#define SCAN_B 256
#define SCAN_NB ((NN + SCAN_B - 1) / SCAN_B)   // 196

typedef __bf16 bf16x8 __attribute__((ext_vector_type(8)));
typedef float f32x4 __attribute__((ext_vector_type(4)));
typedef unsigned short u16x8 __attribute__((ext_vector_type(8)));   // 16 B

static __device__ __forceinline__ unsigned short f2bf(float f) {
    union { float f; unsigned u; } v; v.f = f;
    unsigned r = v.u + 0x7fff + ((v.u >> 16) & 1);   // RNE
    return (unsigned short)(r >> 16);
}
static __device__ __forceinline__ float bf2f(unsigned short u) {
    union { unsigned u; float f; } v; v.u = ((unsigned)u) << 16;
    return v.f;
}

// ---------------- bf16 MFMA GEMM: C16[M,256] = A[M,K] @ Wt[256,K]^T --------
template <int K>
__global__ __launch_bounds__(256)
void gemm_mfma(const ushort* __restrict__ A, const ushort* __restrict__ Wt,
               ushort* __restrict__ C16, int M) {
    __shared__ ushort As[128 * 40];
    __shared__ ushort Bs[128 * 40];
    const int t = threadIdx.x;
    const int bm = blockIdx.x * 128, bn = blockIdx.y * 128;
    const int wv = t >> 6, lane = t & 63;
    const int wm = (wv & 1) * 64, wn = (wv >> 1) * 64;
    const int lrow = lane & 15, quad = lane >> 4;
    const int srow = t >> 2;            // 0..63 staging row
    const int skp = (t & 3) << 3;       // 0,8,16,24 (ushort offset, 8 each)

    f32x4 acc[4][4];
    #pragma unroll
    for (int i = 0; i < 4; ++i)
        #pragma unroll
        for (int j = 0; j < 4; ++j)
            #pragma unroll
            for (int r = 0; r < 4; ++r) acc[i][j][r] = 0.f;

    for (int k0 = 0; k0 < K; k0 += 32) {
        int r0 = bm + srow, r1 = bm + srow + 64;
        u16x8 a0 = (u16x8)(0), a1 = (u16x8)(0);
        if (r0 < M) a0 = *(const u16x8*)(A + (size_t)r0 * K + k0 + skp);
        if (r1 < M) a1 = *(const u16x8*)(A + (size_t)r1 * K + k0 + skp);
        u16x8 b0 = *(const u16x8*)(Wt + (size_t)(bn + srow) * K + k0 + skp);
        u16x8 b1 = *(const u16x8*)(Wt + (size_t)(bn + srow + 64) * K + k0 + skp);
        __syncthreads();
        *(u16x8*)(As + srow * 40 + skp) = a0;
        *(u16x8*)(As + (srow + 64) * 40 + skp) = a1;
        *(u16x8*)(Bs + srow * 40 + skp) = b0;
        *(u16x8*)(Bs + (srow + 64) * 40 + skp) = b1;
        __syncthreads();
        bf16x8 af[4], bf_[4];
        #pragma unroll
        for (int i = 0; i < 4; ++i)
            af[i] = *(const bf16x8*)(As + (wm + i * 16 + lrow) * 40 + quad * 8);
        #pragma unroll
        for (int j = 0; j < 4; ++j)
            bf_[j] = *(const bf16x8*)(Bs + (wn + j * 16 + lrow) * 40 + quad * 8);
        #pragma unroll
        for (int i = 0; i < 4; ++i)
            #pragma unroll
            for (int j = 0; j < 4; ++j)
                acc[i][j] = __builtin_amdgcn_mfma_f32_16x16x32_bf16(
                    af[i], bf_[j], acc[i][j], 0, 0, 0);
    }
    // epilogue: C/D layout col=lane&15, row=quad*4+reg -> bf16 store
    #pragma unroll
    for (int i = 0; i < 4; ++i) {
        int gm0 = bm + wm + i * 16 + quad * 4;
        #pragma unroll
        for (int j = 0; j < 4; ++j) {
            int gn = bn + wn + j * 16 + lrow;
            #pragma unroll
            for (int r = 0; r < 4; ++r)
                if (gm0 + r < M) C16[(size_t)(gm0 + r) * 256 + gn] = f2bf(acc[i][j][r]);
        }
    }
}

// ---------------- conversions ----------------
__global__ void cvt_f32_bf16(const float* __restrict__ in, ushort* __restrict__ out, int n4) {
    int i = blockIdx.x * blockDim.x + threadIdx.x;
    if (i >= n4) return;
    float4 v = ((const float4*)in)[i];
    ushort4 o = make_ushort4(f2bf(v.x), f2bf(v.y), f2bf(v.z), f2bf(v.w));
    ((ushort4*)out)[i] = o;
}

// W[K,256] fp32 -> Wt[256,K] bf16
__global__ void cvt_wt(const float* __restrict__ W, ushort* __restrict__ Wt, int K) {
    int idx = blockIdx.x * blockDim.x + threadIdx.x;
    if (idx >= K * 256) return;
    int n = idx / K, k = idx - n * K;
    Wt[idx] = f2bf(W[(size_t)k * 256 + n]);
}

// --------- per-node attention dots (bf16 h): as[i]=h[i,:]·a_s, ad=·a_d -----
__global__ __launch_bounds__(256)
void attn_dots(const ushort* __restrict__ h, const float* __restrict__ a_s,
               const float* __restrict__ a_d, float* __restrict__ as_out,
               float* __restrict__ ad_out, int n) {
    int wv = (int)((blockIdx.x * blockDim.x + threadIdx.x) >> 6);
    int lane = threadIdx.x & 63;
    if (wv >= n) return;
    ushort4 hx = ((const ushort4*)(h + (size_t)wv * 256))[lane];
    float4 u = ((const float4*)a_s)[lane];
    float4 v = ((const float4*)a_d)[lane];
    float x0 = bf2f(hx.x), x1 = bf2f(hx.y), x2 = bf2f(hx.z), x3 = bf2f(hx.w);
    float s1 = x0 * u.x + x1 * u.y + x2 * u.z + x3 * u.w;
    float s2 = x0 * v.x + x1 * v.y + x2 * v.z + x3 * v.w;
    #pragma unroll
    for (int off = 32; off; off >>= 1) {
        s1 += __shfl_xor(s1, off);
        s2 += __shfl_xor(s2, off);
    }
    if (lane == 0) { as_out[wv] = s1; ad_out[wv] = s2; }
}

// ---------------- CSR build ----------------
__global__ void init_counts(int* __restrict__ counts, int n) {
    int i = blockIdx.x * blockDim.x + threadIdx.x;
    if (i < n) counts[i] = 1;   // self-loop pre-seeded
}

__global__ void hist_kernel(const int* __restrict__ dst, int* __restrict__ counts, int E) {
    int e = blockIdx.x * blockDim.x + threadIdx.x;
    if (e < E) atomicAdd(&counts[dst[e]], 1);
}

// ---- 3-phase parallel exclusive scan of counts[0..n) -> offsets[0..n] ----
// phase A: per-block sums
__global__ __launch_bounds__(SCAN_B)
void scan_partials(const int* __restrict__ counts, int* __restrict__ block_sums, int n) {
    __shared__ int ws_[SCAN_B / 64];
    int i = blockIdx.x * SCAN_B + threadIdx.x;
    int v = (i < n) ? counts[i] : 0;
    #pragma unroll
    for (int off = 32; off; off >>= 1) v += __shfl_xor(v, off);
    int wid = threadIdx.x >> 6;
    if ((threadIdx.x & 63) == 0) ws_[wid] = v;
    __syncthreads();
    if (threadIdx.x == 0) {
        int s = 0;
        #pragma unroll
        for (int w = 0; w < SCAN_B / 64; ++w) s += ws_[w];
        block_sums[blockIdx.x] = s;
    }
}

// phase B: single small block scans the block sums (nb <= 256)
__global__ __launch_bounds__(256)
void scan_block_sums(int* __restrict__ block_sums, int* __restrict__ block_offs,
                     int* __restrict__ offsets_end, int nb, int n) {
    __shared__ int s[256];
    int tid = threadIdx.x;
    int v = (tid < nb) ? block_sums[tid] : 0;
    s[tid] = v;
    __syncthreads();
    for (int d = 1; d < 256; d <<= 1) {
        int t = (tid >= d) ? s[tid - d] : 0;
        __syncthreads();
        s[tid] += t;
        __syncthreads();
    }
    if (tid < nb) block_offs[tid] = s[tid] - v;   // exclusive
    if (tid == 255) *offsets_end = s[255];        // offsets[n] = total
}

// phase C: block-local scan + block offset; also writes cursor copy
__global__ __launch_bounds__(SCAN_B)
void scan_final(const int* __restrict__ counts, const int* __restrict__ block_offs,
                int* __restrict__ offsets, int* __restrict__ cursor, int n) {
    __shared__ int s[SCAN_B];
    int tid = threadIdx.x;
    int i = blockIdx.x * SCAN_B + tid;
    int c = (i < n) ? counts[i] : 0;
    s[tid] = c;
    __syncthreads();
    for (int d = 1; d < SCAN_B; d <<= 1) {
        int t = (tid >= d) ? s[tid - d] : 0;
        __syncthreads();
        s[tid] += t;
        __syncthreads();
    }
    if (i < n) {
        int o = block_offs[blockIdx.x] + s[tid] - c;   // exclusive
        offsets[i] = o;
        cursor[i] = o;
    }
}

__global__ void scatter_kernel(const int* __restrict__ src, const int* __restrict__ dst,
                               int* __restrict__ cursor, int* __restrict__ src_sorted,
                               int E, int n) {
    int e = blockIdx.x * blockDim.x + threadIdx.x;
    if (e < E) {
        int d = dst[e];
        int pos = atomicAdd(&cursor[d], 1);
        src_sorted[pos] = src[e];
    } else if (e < E + n) {
        int i = e - E;
        int pos = atomicAdd(&cursor[i], 1);
        src_sorted[pos] = i;
    }
}

// ---------------- GAT aggregation v2: one wave per dst node ----------------
// Register-resident attention state: src id + logit per lane (deg<=64 fast
// path, essentially always). Pass 3: 2 edges/iter, half-wave 16 B gathers,
// w and s via shuffle (no memory ops besides the row gather).
template <bool ACT, bool BF16OUT>
__global__ __launch_bounds__(256)
void agg_kernel(const ushort* __restrict__ h, const float* __restrict__ as,
                const float* __restrict__ ad, const int* __restrict__ offsets,
                const int* __restrict__ src_sorted, const float* __restrict__ bias,
                float* __restrict__ out, ushort* __restrict__ out16, int n) {
    int wv = (int)((blockIdx.x * blockDim.x + threadIdx.x) >> 6);
    int lane = threadIdx.x & 63;
    if (wv >= n) return;
    int start = offsets[wv], end = offsets[wv + 1];
    int deg = end - start;
    float adn = ad[wv];

    // per-lane edge state for first min(deg,64) edges
    int s_lane = 0;
    float e_lane = -INFINITY;
    if (lane < deg) {
        s_lane = src_sorted[start + lane];
        float e = as[s_lane] + adn;
        e_lane = e > 0.f ? e : 0.2f * e;
    }
    float m = e_lane;
    for (int j = start + 64 + lane; j < end; j += 64) {   // deg>64 tail (rare)
        int s = src_sorted[j];
        float e = as[s] + adn;
        e = e > 0.f ? e : 0.2f * e;
        m = fmaxf(m, e);
    }
    #pragma unroll
    for (int off = 32; off; off >>= 1) m = fmaxf(m, __shfl_xor(m, off));
    float p_lane = __expf(e_lane - m);                    // 0 for inactive lanes
    float denom = p_lane;
    for (int j = start + 64 + lane; j < end; j += 64) {   // rare
        int s = src_sorted[j];
        float e = as[s] + adn;
        e = e > 0.f ? e : 0.2f * e;
        denom += __expf(e - m);
    }
    #pragma unroll
    for (int off = 32; off; off >>= 1) denom += __shfl_xor(denom, off);
    float inv = 1.f / denom;

    // pass 3: lanes 0-31 -> even edge, lanes 32-63 -> odd edge; 16 B/lane
    const int half = lane >> 5;
    const int hl = lane & 31;
    float acc[8] = {0.f, 0.f, 0.f, 0.f, 0.f, 0.f, 0.f, 0.f};
    for (int j0 = 0; j0 < deg; j0 += 2) {
        int myj = j0 + half;
        int src_idx = min(myj, 63);
        float w = __shfl(p_lane, src_idx) * inv;
        int s = __shfl(s_lane, src_idx);
        bool valid = myj < deg;
        if (myj >= 64 && valid) {                         // rare tail
            s = src_sorted[start + myj];
            float e = as[s] + adn;
            e = e > 0.f ? e : 0.2f * e;
            w = __expf(e - m) * inv;
        }
        if (valid) {
            u16x8 row = *(const u16x8*)(h + (size_t)s * 256 + hl * 8);
            #pragma unroll
            for (int k = 0; k < 8; ++k) acc[k] += w * bf2f(row[k]);
        }
    }
    #pragma unroll
    for (int k = 0; k < 8; ++k) acc[k] += __shfl_xor(acc[k], 32);
    if (half == 0) {
        const float4* b4 = (const float4*)bias;
        float4 b0 = b4[hl * 2], b1 = b4[hl * 2 + 1];
        float v[8];
        v[0] = acc[0] + b0.x; v[1] = acc[1] + b0.y; v[2] = acc[2] + b0.z; v[3] = acc[3] + b0.w;
        v[4] = acc[4] + b1.x; v[5] = acc[5] + b1.y; v[6] = acc[6] + b1.z; v[7] = acc[7] + b1.w;
        if (ACT) {
            #pragma unroll
            for (int k = 0; k < 8; ++k) v[k] = v[k] > 0.f ? v[k] : 0.01f * v[k];
        }
        if (BF16OUT) {
            u16x8 o;
            #pragma unroll
            for (int k = 0; k < 8; ++k) o[k] = f2bf(v[k]);
            *(u16x8*)(out16 + (size_t)wv * 256 + hl * 8) = o;
        } else {
            float4 o0 = make_float4(v[0], v[1], v[2], v[3]);
            float4 o1 = make_float4(v[4], v[5], v[6], v[7]);
            float4* op = (float4*)(out + (size_t)wv * 256);
            op[hl * 2] = o0;
            op[hl * 2 + 1] = o1;
        }
    }
}

// ---------------- graph pooling (batch is sorted) ----------------
__global__ void zero_graph_emb(float* __restrict__ graph_emb) {
    graph_emb[blockIdx.x * 256 + threadIdx.x] = 0.f;
}

__global__ __launch_bounds__(256)
void pool_kernel(const float* __restrict__ node_emb, const int* __restrict__ batch,
                 float* __restrict__ graph_emb, int n) {
    int f = threadIdx.x;
    int chunk = (n + gridDim.x - 1) / gridDim.x;
    int i0 = blockIdx.x * chunk;
    int i1 = min(i0 + chunk, n);
    if (i0 >= i1) return;
    float acc = 0.f;
    int cur = batch[i0];
    for (int i = i0; i < i1; ++i) {
        int g = batch[i];
        if (g != cur) {
            atomicAdd(&graph_emb[(size_t)cur * 256 + f], acc);
            acc = 0.f; cur = g;
        }
        acc += node_emb[(size_t)i * 256 + f];
    }
    atomicAdd(&graph_emb[(size_t)cur * 256 + f], acc);
}

static inline char* align_up(char* p, size_t a) {
    return (char*)(((uintptr_t)p + a - 1) & ~(uintptr_t)(a - 1));
}

extern "C" void kernel_launch(void* const* d_in, const int* in_sizes, int n_in,
                              void* d_out, int out_size, void* d_ws, size_t ws_size,
                              hipStream_t stream) {
    const float* x     = (const float*)d_in[0];
    const int* eidx    = (const int*)d_in[1];   // [2, E]: row0=src, row1=dst
    const int* batch   = (const int*)d_in[2];
    const float* W1    = (const float*)d_in[3];
    const float* a_s1  = (const float*)d_in[4];
    const float* a_d1  = (const float*)d_in[5];
    const float* b1    = (const float*)d_in[6];
    const float* W2    = (const float*)d_in[7];
    const float* a_s2  = (const float*)d_in[8];
    const float* a_d2  = (const float*)d_in[9];
    const float* b2    = (const float*)d_in[10];

    float* node_emb  = (float*)d_out;                       // [NN, 256]
    float* graph_emb = node_emb + (size_t)NN * 256;         // [NG, 256]

    char* ws = (char*)d_ws;
    ushort* h16  = (ushort*)ws;  ws += (size_t)NN * 256 * sizeof(ushort);  // gemm out (bf16)
    ws = align_up(ws, 256);
    ushort* z16  = (ushort*)ws;  ws += (size_t)NN * 256 * sizeof(ushort);  // xb, then agg1 out
    ws = align_up(ws, 256);
    ushort* wt1  = (ushort*)ws;  ws += (size_t)256 * F_IN * sizeof(ushort);
    ws = align_up(ws, 256);
    ushort* wt2  = (ushort*)ws;  ws += (size_t)256 * F_HID * sizeof(ushort);
    ws = align_up(ws, 256);
    float* as_buf = (float*)ws;  ws += (size_t)NN * sizeof(float);
    float* ad_buf = (float*)ws;  ws += (size_t)NN * sizeof(float);
    int* counts   = (int*)ws;    ws += (size_t)NN * sizeof(int);
    int* offsets  = (int*)ws;    ws += (size_t)(NN + 1) * sizeof(int);
    ws = align_up(ws, 256);
    int* cursor   = (int*)ws;    ws += (size_t)NN * sizeof(int);
    int* bsum     = (int*)ws;    ws += (size_t)SCAN_NB * sizeof(int);
    int* boff     = (int*)ws;    ws += (size_t)SCAN_NB * sizeof(int);
    ws = align_up(ws, 256);
    int* src_sorted = (int*)ws;  ws += (size_t)(NE + NN) * sizeof(int);

    const int* e_src = eidx;
    const int* e_dst = eidx + NE;

    dim3 gemm_grid((NN + 127) / 128, 2);
    int node_waves_blocks = (NN + 3) / 4;   // 4 waves per 256-thread block

    // ---- CSR build (shared by both layers) ----
    init_counts<<<(NN + 255) / 256, 256, 0, stream>>>(counts, NN);
    hist_kernel<<<(NE + 255) / 256, 256, 0, stream>>>(e_dst, counts, NE);
    scan_partials<<<SCAN_NB, SCAN_B, 0, stream>>>(counts, bsum, NN);
    scan_block_sums<<<1, 256, 0, stream>>>(bsum, boff, offsets + NN, SCAN_NB, NN);
    scan_final<<<SCAN_NB, SCAN_B, 0, stream>>>(counts, boff, offsets, cursor, NN);
    scatter_kernel<<<(NE + NN + 255) / 256, 256, 0, stream>>>(e_src, e_dst, cursor, src_sorted, NE, NN);

    // ---- conversions (xb lives in z16: gemm1 input) ----
    cvt_f32_bf16<<<((NN * F_IN / 4) + 255) / 256, 256, 0, stream>>>(x, z16, NN * F_IN / 4);
    cvt_wt<<<(256 * F_IN + 255) / 256, 256, 0, stream>>>(W1, wt1, F_IN);
    cvt_wt<<<(256 * F_HID + 255) / 256, 256, 0, stream>>>(W2, wt2, F_HID);

    // ---- layer 1 ----
    gemm_mfma<F_IN><<<gemm_grid, 256, 0, stream>>>(z16, wt1, h16, NN);
    attn_dots<<<node_waves_blocks, 256, 0, stream>>>(h16, a_s1, a_d1, as_buf, ad_buf, NN);
    agg_kernel<true, true><<<node_waves_blocks, 256, 0, stream>>>(h16, as_buf, ad_buf, offsets,
                                                                  src_sorted, b1, nullptr, z16, NN);
    // ---- layer 2 ----
    gemm_mfma<F_HID><<<gemm_grid, 256, 0, stream>>>(z16, wt2, h16, NN);
    attn_dots<<<node_waves_blocks, 256, 0, stream>>>(h16, a_s2, a_d2, as_buf, ad_buf, NN);
    agg_kernel<false, false><<<node_waves_blocks, 256, 0, stream>>>(h16, as_buf, ad_buf, offsets,
                                                                    src_sorted, b2, node_emb, nullptr, NN);
    // ---- pool ----
    zero_graph_emb<<<NG, 256, 0, stream>>>(graph_emb);
    pool_kernel<<<512, 256, 0, stream>>>(node_emb, batch, graph_emb, NN);
}

// Round 8
// 420.161 us; speedup vs baseline: 2.1994x; 1.0092x over previous
//
#include <hip/hip_runtime.h>
#include <math.h>

// Problem constants (fixed by reference)
#define NN 50000
#define NE 800000
#define F_IN 128
#define F_HID 256
#define NG 64
#define SCAN_B 256
#define SCAN_NB ((NN + SCAN_B - 1) / SCAN_B)   // 196

typedef __bf16 bf16x8 __attribute__((ext_vector_type(8)));
typedef float f32x4 __attribute__((ext_vector_type(4)));
typedef unsigned short u16x8 __attribute__((ext_vector_type(8)));   // 16 B

static __device__ __forceinline__ unsigned short f2bf(float f) {
    union { float f; unsigned u; } v; v.f = f;
    unsigned r = v.u + 0x7fff + ((v.u >> 16) & 1);   // RNE
    return (unsigned short)(r >> 16);
}
static __device__ __forceinline__ float bf2f(unsigned short u) {
    union { unsigned u; float f; } v; v.u = ((unsigned)u) << 16;
    return v.f;
}

// ------- bf16 MFMA GEMM + fused attention dots ------------------------------
// C16[M,256] = A[M,K] @ Wt[256,K]^T (bf16 in, bf16 out, fp32 acc).
// Epilogue also computes as[m] += h[m,:]·a_s, ad[m] += h[m,:]·a_d from the
// fp32 accumulators (shuffle-reduce over lrow, atomicAdd per row partial).
template <int K>
__global__ __launch_bounds__(256)
void gemm_mfma(const ushort* __restrict__ A, const ushort* __restrict__ Wt,
               ushort* __restrict__ C16, const float* __restrict__ a_s,
               const float* __restrict__ a_d, float* __restrict__ as_out,
               float* __restrict__ ad_out, int M) {
    __shared__ ushort As[128 * 40];
    __shared__ ushort Bs[128 * 40];
    const int t = threadIdx.x;
    const int bm = blockIdx.x * 128, bn = blockIdx.y * 128;
    const int wv = t >> 6, lane = t & 63;
    const int wm = (wv & 1) * 64, wn = (wv >> 1) * 64;
    const int lrow = lane & 15, quad = lane >> 4;
    const int srow = t >> 2;            // 0..63 staging row
    const int skp = (t & 3) << 3;       // 0,8,16,24 (ushort offset, 8 each)

    f32x4 acc[4][4];
    #pragma unroll
    for (int i = 0; i < 4; ++i)
        #pragma unroll
        for (int j = 0; j < 4; ++j)
            #pragma unroll
            for (int r = 0; r < 4; ++r) acc[i][j][r] = 0.f;

    for (int k0 = 0; k0 < K; k0 += 32) {
        int r0 = bm + srow, r1 = bm + srow + 64;
        u16x8 a0 = (u16x8)(0), a1 = (u16x8)(0);
        if (r0 < M) a0 = *(const u16x8*)(A + (size_t)r0 * K + k0 + skp);
        if (r1 < M) a1 = *(const u16x8*)(A + (size_t)r1 * K + k0 + skp);
        u16x8 b0 = *(const u16x8*)(Wt + (size_t)(bn + srow) * K + k0 + skp);
        u16x8 b1 = *(const u16x8*)(Wt + (size_t)(bn + srow + 64) * K + k0 + skp);
        __syncthreads();
        *(u16x8*)(As + srow * 40 + skp) = a0;
        *(u16x8*)(As + (srow + 64) * 40 + skp) = a1;
        *(u16x8*)(Bs + srow * 40 + skp) = b0;
        *(u16x8*)(Bs + (srow + 64) * 40 + skp) = b1;
        __syncthreads();
        bf16x8 af[4], bf_[4];
        #pragma unroll
        for (int i = 0; i < 4; ++i)
            af[i] = *(const bf16x8*)(As + (wm + i * 16 + lrow) * 40 + quad * 8);
        #pragma unroll
        for (int j = 0; j < 4; ++j)
            bf_[j] = *(const bf16x8*)(Bs + (wn + j * 16 + lrow) * 40 + quad * 8);
        #pragma unroll
        for (int i = 0; i < 4; ++i)
            #pragma unroll
            for (int j = 0; j < 4; ++j)
                acc[i][j] = __builtin_amdgcn_mfma_f32_16x16x32_bf16(
                    af[i], bf_[j], acc[i][j], 0, 0, 0);
    }
    // fused attention dots: this lane covers cols wn+j*16+lrow
    float asf[4], adf[4];
    #pragma unroll
    for (int j = 0; j < 4; ++j) {
        asf[j] = a_s[bn + wn + j * 16 + lrow];
        adf[j] = a_d[bn + wn + j * 16 + lrow];
    }
    // epilogue: C/D layout col=lane&15, row=quad*4+reg -> bf16 store + dots
    #pragma unroll
    for (int i = 0; i < 4; ++i) {
        int gm0 = bm + wm + i * 16 + quad * 4;
        #pragma unroll
        for (int r = 0; r < 4; ++r) {
            float ps = 0.f, pd = 0.f;
            #pragma unroll
            for (int j = 0; j < 4; ++j) {
                ps += acc[i][j][r] * asf[j];
                pd += acc[i][j][r] * adf[j];
            }
            #pragma unroll
            for (int off = 8; off; off >>= 1) {
                ps += __shfl_xor(ps, off);
                pd += __shfl_xor(pd, off);
            }
            if (lrow == 0 && gm0 + r < M) {
                atomicAdd(&as_out[gm0 + r], ps);
                atomicAdd(&ad_out[gm0 + r], pd);
            }
        }
        #pragma unroll
        for (int j = 0; j < 4; ++j) {
            int gn = bn + wn + j * 16 + lrow;
            #pragma unroll
            for (int r = 0; r < 4; ++r)
                if (gm0 + r < M) C16[(size_t)(gm0 + r) * 256 + gn] = f2bf(acc[i][j][r]);
        }
    }
}

// ---------------- conversions ----------------
__global__ void cvt_f32_bf16(const float* __restrict__ in, ushort* __restrict__ out, int n4) {
    int i = blockIdx.x * blockDim.x + threadIdx.x;
    if (i >= n4) return;
    float4 v = ((const float4*)in)[i];
    ushort4 o = make_ushort4(f2bf(v.x), f2bf(v.y), f2bf(v.z), f2bf(v.w));
    ((ushort4*)out)[i] = o;
}

// W[K,256] fp32 -> Wt[256,K] bf16
__global__ void cvt_wt(const float* __restrict__ W, ushort* __restrict__ Wt, int K) {
    int idx = blockIdx.x * blockDim.x + threadIdx.x;
    if (idx >= K * 256) return;
    int n = idx / K, k = idx - n * K;
    Wt[idx] = f2bf(W[(size_t)k * 256 + n]);
}

__global__ void zero_asad(float* __restrict__ a, float* __restrict__ b, int n) {
    int i = blockIdx.x * blockDim.x + threadIdx.x;
    if (i < n) { a[i] = 0.f; b[i] = 0.f; }
}

// ---------------- CSR build ----------------
__global__ void init_counts(int* __restrict__ counts, int n) {
    int i = blockIdx.x * blockDim.x + threadIdx.x;
    if (i < n) counts[i] = 1;   // self-loop pre-seeded
}

__global__ void hist_kernel(const int* __restrict__ dst, int* __restrict__ counts, int E) {
    int e = blockIdx.x * blockDim.x + threadIdx.x;
    if (e < E) atomicAdd(&counts[dst[e]], 1);
}

// ---- 3-phase parallel exclusive scan of counts[0..n) -> offsets[0..n] ----
__global__ __launch_bounds__(SCAN_B)
void scan_partials(const int* __restrict__ counts, int* __restrict__ block_sums, int n) {
    __shared__ int ws_[SCAN_B / 64];
    int i = blockIdx.x * SCAN_B + threadIdx.x;
    int v = (i < n) ? counts[i] : 0;
    #pragma unroll
    for (int off = 32; off; off >>= 1) v += __shfl_xor(v, off);
    int wid = threadIdx.x >> 6;
    if ((threadIdx.x & 63) == 0) ws_[wid] = v;
    __syncthreads();
    if (threadIdx.x == 0) {
        int s = 0;
        #pragma unroll
        for (int w = 0; w < SCAN_B / 64; ++w) s += ws_[w];
        block_sums[blockIdx.x] = s;
    }
}

__global__ __launch_bounds__(256)
void scan_block_sums(int* __restrict__ block_sums, int* __restrict__ block_offs,
                     int* __restrict__ offsets_end, int nb, int n) {
    __shared__ int s[256];
    int tid = threadIdx.x;
    int v = (tid < nb) ? block_sums[tid] : 0;
    s[tid] = v;
    __syncthreads();
    for (int d = 1; d < 256; d <<= 1) {
        int t = (tid >= d) ? s[tid - d] : 0;
        __syncthreads();
        s[tid] += t;
        __syncthreads();
    }
    if (tid < nb) block_offs[tid] = s[tid] - v;   // exclusive
    if (tid == 255) *offsets_end = s[255];        // offsets[n] = total
}

__global__ __launch_bounds__(SCAN_B)
void scan_final(const int* __restrict__ counts, const int* __restrict__ block_offs,
                int* __restrict__ offsets, int* __restrict__ cursor, int n) {
    __shared__ int s[SCAN_B];
    int tid = threadIdx.x;
    int i = blockIdx.x * SCAN_B + tid;
    int c = (i < n) ? counts[i] : 0;
    s[tid] = c;
    __syncthreads();
    for (int d = 1; d < SCAN_B; d <<= 1) {
        int t = (tid >= d) ? s[tid - d] : 0;
        __syncthreads();
        s[tid] += t;
        __syncthreads();
    }
    if (i < n) {
        int o = block_offs[blockIdx.x] + s[tid] - c;   // exclusive
        offsets[i] = o;
        cursor[i] = o;
    }
}

__global__ void scatter_kernel(const int* __restrict__ src, const int* __restrict__ dst,
                               int* __restrict__ cursor, int* __restrict__ src_sorted,
                               int E, int n) {
    int e = blockIdx.x * blockDim.x + threadIdx.x;
    if (e < E) {
        int d = dst[e];
        int pos = atomicAdd(&cursor[d], 1);
        src_sorted[pos] = src[e];
    } else if (e < E + n) {
        int i = e - E;
        int pos = atomicAdd(&cursor[i], 1);
        src_sorted[pos] = i;
    }
}

// ---------------- GAT aggregation v3: one wave per dst node ----------------
// Register-resident logits (deg<=64 fast path). Pass 3: 4 edges in flight
// (2x unrolled half-wave 16 B gathers, independent accumulators).
template <bool ACT, bool BF16OUT>
__global__ __launch_bounds__(256)
void agg_kernel(const ushort* __restrict__ h, const float* __restrict__ as,
                const float* __restrict__ ad, const int* __restrict__ offsets,
                const int* __restrict__ src_sorted, const float* __restrict__ bias,
                float* __restrict__ out, ushort* __restrict__ out16, int n) {
    int wv = (int)((blockIdx.x * blockDim.x + threadIdx.x) >> 6);
    int lane = threadIdx.x & 63;
    if (wv >= n) return;
    int start = offsets[wv], end = offsets[wv + 1];
    int deg = end - start;
    float adn = ad[wv];

    // per-lane edge state for first min(deg,64) edges
    int s_lane = 0;
    float e_lane = -INFINITY;
    if (lane < deg) {
        s_lane = src_sorted[start + lane];
        float e = as[s_lane] + adn;
        e_lane = e > 0.f ? e : 0.2f * e;
    }
    float m = e_lane;
    for (int j = start + 64 + lane; j < end; j += 64) {   // deg>64 tail (rare)
        int s = src_sorted[j];
        float e = as[s] + adn;
        e = e > 0.f ? e : 0.2f * e;
        m = fmaxf(m, e);
    }
    #pragma unroll
    for (int off = 32; off; off >>= 1) m = fmaxf(m, __shfl_xor(m, off));
    float p_lane = __expf(e_lane - m);                    // 0 for inactive lanes
    float denom = p_lane;
    for (int j = start + 64 + lane; j < end; j += 64) {   // rare
        int s = src_sorted[j];
        float e = as[s] + adn;
        e = e > 0.f ? e : 0.2f * e;
        denom += __expf(e - m);
    }
    #pragma unroll
    for (int off = 32; off; off >>= 1) denom += __shfl_xor(denom, off);
    float inv = 1.f / denom;
    p_lane *= inv;                                        // normalized weight

    // pass 3: lanes 0-31 -> even edge, lanes 32-63 -> odd edge; 16 B/lane
    const int half = lane >> 5;
    const int hl = lane & 31;
    const int degc = min(deg, 64);
    float acc0[8] = {0.f, 0.f, 0.f, 0.f, 0.f, 0.f, 0.f, 0.f};
    float acc1[8] = {0.f, 0.f, 0.f, 0.f, 0.f, 0.f, 0.f, 0.f};
    int j0 = 0;
    for (; j0 + 4 <= degc; j0 += 4) {                     // 4 edges in flight
        int jA = j0 + half, jB = j0 + 2 + half;
        float wA = __shfl(p_lane, jA);
        int sA = __shfl(s_lane, jA);
        float wB = __shfl(p_lane, jB);
        int sB = __shfl(s_lane, jB);
        u16x8 rA = *(const u16x8*)(h + (size_t)sA * 256 + hl * 8);
        u16x8 rB = *(const u16x8*)(h + (size_t)sB * 256 + hl * 8);
        #pragma unroll
        for (int k = 0; k < 8; ++k) acc0[k] += wA * bf2f(rA[k]);
        #pragma unroll
        for (int k = 0; k < 8; ++k) acc1[k] += wB * bf2f(rB[k]);
    }
    for (; j0 < degc; j0 += 2) {                          // 0-3 remainder
        int myj = j0 + half;
        int idx = min(myj, 63);
        float w = __shfl(p_lane, idx);
        int s = __shfl(s_lane, idx);
        if (myj < degc) {
            u16x8 row = *(const u16x8*)(h + (size_t)s * 256 + hl * 8);
            #pragma unroll
            for (int k = 0; k < 8; ++k) acc0[k] += w * bf2f(row[k]);
        }
    }
    for (int j = 64 + half; j < deg; j += 2) {            // rare deg>64 tail
        int s = src_sorted[start + j];
        float e = as[s] + adn;
        e = e > 0.f ? e : 0.2f * e;
        float w = __expf(e - m) * inv;
        u16x8 row = *(const u16x8*)(h + (size_t)s * 256 + hl * 8);
        #pragma unroll
        for (int k = 0; k < 8; ++k) acc0[k] += w * bf2f(row[k]);
    }
    #pragma unroll
    for (int k = 0; k < 8; ++k) {
        acc0[k] += acc1[k];
        acc0[k] += __shfl_xor(acc0[k], 32);
    }
    if (half == 0) {
        const float4* b4 = (const float4*)bias;
        float4 b0 = b4[hl * 2], b1 = b4[hl * 2 + 1];
        float v[8];
        v[0] = acc0[0] + b0.x; v[1] = acc0[1] + b0.y; v[2] = acc0[2] + b0.z; v[3] = acc0[3] + b0.w;
        v[4] = acc0[4] + b1.x; v[5] = acc0[5] + b1.y; v[6] = acc0[6] + b1.z; v[7] = acc0[7] + b1.w;
        if (ACT) {
            #pragma unroll
            for (int k = 0; k < 8; ++k) v[k] = v[k] > 0.f ? v[k] : 0.01f * v[k];
        }
        if (BF16OUT) {
            u16x8 o;
            #pragma unroll
            for (int k = 0; k < 8; ++k) o[k] = f2bf(v[k]);
            *(u16x8*)(out16 + (size_t)wv * 256 + hl * 8) = o;
        } else {
            float4 o0 = make_float4(v[0], v[1], v[2], v[3]);
            float4 o1 = make_float4(v[4], v[5], v[6], v[7]);
            float4* op = (float4*)(out + (size_t)wv * 256);
            op[hl * 2] = o0;
            op[hl * 2 + 1] = o1;
        }
    }
}

// ---------------- graph pooling (batch is sorted) ----------------
__global__ void zero_graph_emb(float* __restrict__ graph_emb) {
    graph_emb[blockIdx.x * 256 + threadIdx.x] = 0.f;
}

__global__ __launch_bounds__(256)
void pool_kernel(const float* __restrict__ node_emb, const int* __restrict__ batch,
                 float* __restrict__ graph_emb, int n) {
    int f = threadIdx.x;
    int chunk = (n + gridDim.x - 1) / gridDim.x;
    int i0 = blockIdx.x * chunk;
    int i1 = min(i0 + chunk, n);
    if (i0 >= i1) return;
    float acc = 0.f;
    int cur = batch[i0];
    for (int i = i0; i < i1; ++i) {
        int g = batch[i];
        if (g != cur) {
            atomicAdd(&graph_emb[(size_t)cur * 256 + f], acc);
            acc = 0.f; cur = g;
        }
        acc += node_emb[(size_t)i * 256 + f];
    }
    atomicAdd(&graph_emb[(size_t)cur * 256 + f], acc);
}

static inline char* align_up(char* p, size_t a) {
    return (char*)(((uintptr_t)p + a - 1) & ~(uintptr_t)(a - 1));
}

extern "C" void kernel_launch(void* const* d_in, const int* in_sizes, int n_in,
                              void* d_out, int out_size, void* d_ws, size_t ws_size,
                              hipStream_t stream) {
    const float* x     = (const float*)d_in[0];
    const int* eidx    = (const int*)d_in[1];   // [2, E]: row0=src, row1=dst
    const int* batch   = (const int*)d_in[2];
    const float* W1    = (const float*)d_in[3];
    const float* a_s1  = (const float*)d_in[4];
    const float* a_d1  = (const float*)d_in[5];
    const float* b1    = (const float*)d_in[6];
    const float* W2    = (const float*)d_in[7];
    const float* a_s2  = (const float*)d_in[8];
    const float* a_d2  = (const float*)d_in[9];
    const float* b2    = (const float*)d_in[10];

    float* node_emb  = (float*)d_out;                       // [NN, 256]
    float* graph_emb = node_emb + (size_t)NN * 256;         // [NG, 256]

    char* ws = (char*)d_ws;
    ushort* h16  = (ushort*)ws;  ws += (size_t)NN * 256 * sizeof(ushort);  // gemm out (bf16)
    ws = align_up(ws, 256);
    ushort* z16  = (ushort*)ws;  ws += (size_t)NN * 256 * sizeof(ushort);  // xb, then agg1 out
    ws = align_up(ws, 256);
    ushort* wt1  = (ushort*)ws;  ws += (size_t)256 * F_IN * sizeof(ushort);
    ws = align_up(ws, 256);
    ushort* wt2  = (ushort*)ws;  ws += (size_t)256 * F_HID * sizeof(ushort);
    ws = align_up(ws, 256);
    float* as_buf = (float*)ws;  ws += (size_t)NN * sizeof(float);
    float* ad_buf = (float*)ws;  ws += (size_t)NN * sizeof(float);
    int* counts   = (int*)ws;    ws += (size_t)NN * sizeof(int);
    int* offsets  = (int*)ws;    ws += (size_t)(NN + 1) * sizeof(int);
    ws = align_up(ws, 256);
    int* cursor   = (int*)ws;    ws += (size_t)NN * sizeof(int);
    int* bsum     = (int*)ws;    ws += (size_t)SCAN_NB * sizeof(int);
    int* boff     = (int*)ws;    ws += (size_t)SCAN_NB * sizeof(int);
    ws = align_up(ws, 256);
    int* src_sorted = (int*)ws;  ws += (size_t)(NE + NN) * sizeof(int);

    const int* e_src = eidx;
    const int* e_dst = eidx + NE;

    dim3 gemm_grid((NN + 127) / 128, 2);
    int node_waves_blocks = (NN + 3) / 4;   // 4 waves per 256-thread block

    // ---- CSR build (shared by both layers) ----
    init_counts<<<(NN + 255) / 256, 256, 0, stream>>>(counts, NN);
    hist_kernel<<<(NE + 255) / 256, 256, 0, stream>>>(e_dst, counts, NE);
    scan_partials<<<SCAN_NB, SCAN_B, 0, stream>>>(counts, bsum, NN);
    scan_block_sums<<<1, 256, 0, stream>>>(bsum, boff, offsets + NN, SCAN_NB, NN);
    scan_final<<<SCAN_NB, SCAN_B, 0, stream>>>(counts, boff, offsets, cursor, NN);
    scatter_kernel<<<(NE + NN + 255) / 256, 256, 0, stream>>>(e_src, e_dst, cursor, src_sorted, NE, NN);

    // ---- conversions (xb lives in z16: gemm1 input) ----
    cvt_f32_bf16<<<((NN * F_IN / 4) + 255) / 256, 256, 0, stream>>>(x, z16, NN * F_IN / 4);
    cvt_wt<<<(256 * F_IN + 255) / 256, 256, 0, stream>>>(W1, wt1, F_IN);
    cvt_wt<<<(256 * F_HID + 255) / 256, 256, 0, stream>>>(W2, wt2, F_HID);

    // ---- layer 1 ----
    zero_asad<<<(NN + 255) / 256, 256, 0, stream>>>(as_buf, ad_buf, NN);
    gemm_mfma<F_IN><<<gemm_grid, 256, 0, stream>>>(z16, wt1, h16, a_s1, a_d1, as_buf, ad_buf, NN);
    agg_kernel<true, true><<<node_waves_blocks, 256, 0, stream>>>(h16, as_buf, ad_buf, offsets,
                                                                  src_sorted, b1, nullptr, z16, NN);
    // ---- layer 2 ----
    zero_asad<<<(NN + 255) / 256, 256, 0, stream>>>(as_buf, ad_buf, NN);
    gemm_mfma<F_HID><<<gemm_grid, 256, 0, stream>>>(z16, wt2, h16, a_s2, a_d2, as_buf, ad_buf, NN);
    agg_kernel<false, false><<<node_waves_blocks, 256, 0, stream>>>(h16, as_buf, ad_buf, offsets,
                                                                    src_sorted, b2, node_emb, nullptr, NN);
    // ---- pool ----
    zero_graph_emb<<<NG, 256, 0, stream>>>(graph_emb);
    pool_kernel<<<512, 256, 0, stream>>>(node_emb, batch, graph_emb, NN);
}

// Round 9
// 398.383 us; speedup vs baseline: 2.3197x; 1.0547x over previous
//
#include <hip/hip_runtime.h>
#include <math.h>

// Problem constants (fixed by reference)
#define NN 50000
#define NE 800000
#define F_IN 128
#define F_HID 256
#define NG 64
#define SCAN_B 256
#define SCAN_NB ((NN + SCAN_B - 1) / SCAN_B)   // 196

typedef __bf16 bf16x8 __attribute__((ext_vector_type(8)));
typedef float f32x4 __attribute__((ext_vector_type(4)));
typedef unsigned short u16x8 __attribute__((ext_vector_type(8)));   // 16 B

static __device__ __forceinline__ unsigned short f2bf(float f) {
    union { float f; unsigned u; } v; v.f = f;
    unsigned r = v.u + 0x7fff + ((v.u >> 16) & 1);   // RNE
    return (unsigned short)(r >> 16);
}
static __device__ __forceinline__ float bf2f(unsigned short u) {
    union { unsigned u; float f; } v; v.u = ((unsigned)u) << 16;
    return v.f;
}

// ------- bf16 MFMA GEMM + fused attention dots ------------------------------
// C16[M,256] = A[M,K] @ Wt[256,K]^T (fp32 acc, bf16 out). AF32: A is fp32 and
// is converted to bf16 in-register during staging (fuses the cvt pass).
// K-loop software-pipelined: next iter's global tiles prefetch into registers
// during the MFMA section. Epilogue fuses as/ad attention dots.
template <int K, bool AF32>
__global__ __launch_bounds__(256)
void gemm_mfma(const void* __restrict__ Ap, const ushort* __restrict__ Wt,
               ushort* __restrict__ C16, const float* __restrict__ a_s,
               const float* __restrict__ a_d, float* __restrict__ as_out,
               float* __restrict__ ad_out, int M) {
    const ushort* A16 = (const ushort*)Ap;
    const float* A32 = (const float*)Ap;
    __shared__ ushort As[128 * 40];
    __shared__ ushort Bs[128 * 40];
    const int t = threadIdx.x;
    const int bm = blockIdx.x * 128, bn = blockIdx.y * 128;
    const int wv = t >> 6, lane = t & 63;
    const int wm = (wv & 1) * 64, wn = (wv >> 1) * 64;
    const int lrow = lane & 15, quad = lane >> 4;
    const int srow = t >> 2;            // 0..63 staging row
    const int skp = (t & 3) << 3;       // 0,8,16,24 (element offset, 8 each)

    f32x4 acc[4][4];
    #pragma unroll
    for (int i = 0; i < 4; ++i)
        #pragma unroll
        for (int j = 0; j < 4; ++j)
            #pragma unroll
            for (int r = 0; r < 4; ++r) acc[i][j][r] = 0.f;

    const int r0 = bm + srow, r1 = bm + srow + 64;
    const int rb0 = bn + srow, rb1 = bn + srow + 64;

    auto load_a = [&](int k0, u16x8& a0, u16x8& a1) {
        a0 = (u16x8)(0); a1 = (u16x8)(0);
        if (AF32) {
            if (r0 < M) {
                const float* p = A32 + (size_t)r0 * K + k0 + skp;
                float4 f0 = *(const float4*)p, f1 = *(const float4*)(p + 4);
                a0[0]=f2bf(f0.x); a0[1]=f2bf(f0.y); a0[2]=f2bf(f0.z); a0[3]=f2bf(f0.w);
                a0[4]=f2bf(f1.x); a0[5]=f2bf(f1.y); a0[6]=f2bf(f1.z); a0[7]=f2bf(f1.w);
            }
            if (r1 < M) {
                const float* p = A32 + (size_t)r1 * K + k0 + skp;
                float4 f0 = *(const float4*)p, f1 = *(const float4*)(p + 4);
                a1[0]=f2bf(f0.x); a1[1]=f2bf(f0.y); a1[2]=f2bf(f0.z); a1[3]=f2bf(f0.w);
                a1[4]=f2bf(f1.x); a1[5]=f2bf(f1.y); a1[6]=f2bf(f1.z); a1[7]=f2bf(f1.w);
            }
        } else {
            if (r0 < M) a0 = *(const u16x8*)(A16 + (size_t)r0 * K + k0 + skp);
            if (r1 < M) a1 = *(const u16x8*)(A16 + (size_t)r1 * K + k0 + skp);
        }
    };

    u16x8 a0, a1, b0, b1;
    load_a(0, a0, a1);
    b0 = *(const u16x8*)(Wt + (size_t)rb0 * K + skp);
    b1 = *(const u16x8*)(Wt + (size_t)rb1 * K + skp);

    for (int k0 = 0; k0 < K; k0 += 32) {
        __syncthreads();   // previous iter's LDS reads complete
        *(u16x8*)(As + srow * 40 + skp) = a0;
        *(u16x8*)(As + (srow + 64) * 40 + skp) = a1;
        *(u16x8*)(Bs + srow * 40 + skp) = b0;
        *(u16x8*)(Bs + (srow + 64) * 40 + skp) = b1;
        __syncthreads();
        bool more = (k0 + 32) < K;
        u16x8 na0, na1, nb0, nb1;
        if (more) {        // prefetch overlaps the MFMA section below
            load_a(k0 + 32, na0, na1);
            nb0 = *(const u16x8*)(Wt + (size_t)rb0 * K + k0 + 32 + skp);
            nb1 = *(const u16x8*)(Wt + (size_t)rb1 * K + k0 + 32 + skp);
        }
        bf16x8 af[4], bf_[4];
        #pragma unroll
        for (int i = 0; i < 4; ++i)
            af[i] = *(const bf16x8*)(As + (wm + i * 16 + lrow) * 40 + quad * 8);
        #pragma unroll
        for (int j = 0; j < 4; ++j)
            bf_[j] = *(const bf16x8*)(Bs + (wn + j * 16 + lrow) * 40 + quad * 8);
        #pragma unroll
        for (int i = 0; i < 4; ++i)
            #pragma unroll
            for (int j = 0; j < 4; ++j)
                acc[i][j] = __builtin_amdgcn_mfma_f32_16x16x32_bf16(
                    af[i], bf_[j], acc[i][j], 0, 0, 0);
        if (more) { a0 = na0; a1 = na1; b0 = nb0; b1 = nb1; }
    }
    // fused attention dots: this lane covers cols wn+j*16+lrow
    float asf[4], adf[4];
    #pragma unroll
    for (int j = 0; j < 4; ++j) {
        asf[j] = a_s[bn + wn + j * 16 + lrow];
        adf[j] = a_d[bn + wn + j * 16 + lrow];
    }
    // epilogue: C/D layout col=lane&15, row=quad*4+reg -> bf16 store + dots
    #pragma unroll
    for (int i = 0; i < 4; ++i) {
        int gm0 = bm + wm + i * 16 + quad * 4;
        #pragma unroll
        for (int r = 0; r < 4; ++r) {
            float ps = 0.f, pd = 0.f;
            #pragma unroll
            for (int j = 0; j < 4; ++j) {
                ps += acc[i][j][r] * asf[j];
                pd += acc[i][j][r] * adf[j];
            }
            #pragma unroll
            for (int off = 8; off; off >>= 1) {
                ps += __shfl_xor(ps, off);
                pd += __shfl_xor(pd, off);
            }
            if (lrow == 0 && gm0 + r < M) {
                atomicAdd(&as_out[gm0 + r], ps);
                atomicAdd(&ad_out[gm0 + r], pd);
            }
        }
        #pragma unroll
        for (int j = 0; j < 4; ++j) {
            int gn = bn + wn + j * 16 + lrow;
            #pragma unroll
            for (int r = 0; r < 4; ++r)
                if (gm0 + r < M) C16[(size_t)(gm0 + r) * 256 + gn] = f2bf(acc[i][j][r]);
        }
    }
}

// W1[128,256] and W2[256,256] fp32 -> Wt bf16 [256,K] transposed, one launch
__global__ void cvt_wts(const float* __restrict__ W1, ushort* __restrict__ Wt1,
                        const float* __restrict__ W2, ushort* __restrict__ Wt2) {
    int idx = blockIdx.x * blockDim.x + threadIdx.x;
    if (idx < 256 * F_IN) {
        int n = idx / F_IN, k = idx - n * F_IN;
        Wt1[idx] = f2bf(W1[(size_t)k * 256 + n]);
    } else if (idx < 256 * F_IN + 256 * F_HID) {
        int i2 = idx - 256 * F_IN;
        int n = i2 / F_HID, k = i2 - n * F_HID;
        Wt2[i2] = f2bf(W2[(size_t)k * 256 + n]);
    }
}

// ---------------- CSR build (counts pre-zeroed by memset) ----------------
__global__ void hist_kernel(const int* __restrict__ dst, int* __restrict__ counts,
                            int E, int n) {
    int e = blockIdx.x * blockDim.x + threadIdx.x;
    if (e < E) atomicAdd(&counts[dst[e]], 1);
    else if (e < E + n) atomicAdd(&counts[e - E], 1);   // self-loop
}

// ---- 3-phase parallel exclusive scan of counts[0..n) -> offsets[0..n] ----
__global__ __launch_bounds__(SCAN_B)
void scan_partials(const int* __restrict__ counts, int* __restrict__ block_sums, int n) {
    __shared__ int ws_[SCAN_B / 64];
    int i = blockIdx.x * SCAN_B + threadIdx.x;
    int v = (i < n) ? counts[i] : 0;
    #pragma unroll
    for (int off = 32; off; off >>= 1) v += __shfl_xor(v, off);
    int wid = threadIdx.x >> 6;
    if ((threadIdx.x & 63) == 0) ws_[wid] = v;
    __syncthreads();
    if (threadIdx.x == 0) {
        int s = 0;
        #pragma unroll
        for (int w = 0; w < SCAN_B / 64; ++w) s += ws_[w];
        block_sums[blockIdx.x] = s;
    }
}

__global__ __launch_bounds__(256)
void scan_block_sums(int* __restrict__ block_sums, int* __restrict__ block_offs,
                     int* __restrict__ offsets_end, int nb, int n) {
    __shared__ int s[256];
    int tid = threadIdx.x;
    int v = (tid < nb) ? block_sums[tid] : 0;
    s[tid] = v;
    __syncthreads();
    for (int d = 1; d < 256; d <<= 1) {
        int t = (tid >= d) ? s[tid - d] : 0;
        __syncthreads();
        s[tid] += t;
        __syncthreads();
    }
    if (tid < nb) block_offs[tid] = s[tid] - v;   // exclusive
    if (tid == 255) *offsets_end = s[255];        // offsets[n] = total
}

__global__ __launch_bounds__(SCAN_B)
void scan_final(const int* __restrict__ counts, const int* __restrict__ block_offs,
                int* __restrict__ offsets, int* __restrict__ cursor, int n) {
    __shared__ int s[SCAN_B];
    int tid = threadIdx.x;
    int i = blockIdx.x * SCAN_B + tid;
    int c = (i < n) ? counts[i] : 0;
    s[tid] = c;
    __syncthreads();
    for (int d = 1; d < SCAN_B; d <<= 1) {
        int t = (tid >= d) ? s[tid - d] : 0;
        __syncthreads();
        s[tid] += t;
        __syncthreads();
    }
    if (i < n) {
        int o = block_offs[blockIdx.x] + s[tid] - c;   // exclusive
        offsets[i] = o;
        cursor[i] = o;
    }
}

__global__ void scatter_kernel(const int* __restrict__ src, const int* __restrict__ dst,
                               int* __restrict__ cursor, int* __restrict__ src_sorted,
                               int E, int n) {
    int e = blockIdx.x * blockDim.x + threadIdx.x;
    if (e < E) {
        int d = dst[e];
        int pos = atomicAdd(&cursor[d], 1);
        src_sorted[pos] = src[e];
    } else if (e < E + n) {
        int i = e - E;
        int pos = atomicAdd(&cursor[i], 1);
        src_sorted[pos] = i;
    }
}

// ---------------- GAT aggregation: one wave per dst node ----------------
// Register-resident logits (deg<=64 fast path); pass 3: 2 edges/iter,
// half-wave 16 B gathers, pre-normalized weights via shuffle.
template <bool ACT, bool BF16OUT>
__global__ __launch_bounds__(256)
void agg_kernel(const ushort* __restrict__ h, const float* __restrict__ as,
                const float* __restrict__ ad, const int* __restrict__ offsets,
                const int* __restrict__ src_sorted, const float* __restrict__ bias,
                float* __restrict__ out, ushort* __restrict__ out16, int n) {
    int wv = (int)((blockIdx.x * blockDim.x + threadIdx.x) >> 6);
    int lane = threadIdx.x & 63;
    if (wv >= n) return;
    int start = offsets[wv], end = offsets[wv + 1];
    int deg = end - start;
    float adn = ad[wv];

    int s_lane = 0;
    float e_lane = -INFINITY;
    if (lane < deg) {
        s_lane = src_sorted[start + lane];
        float e = as[s_lane] + adn;
        e_lane = e > 0.f ? e : 0.2f * e;
    }
    float m = e_lane;
    for (int j = start + 64 + lane; j < end; j += 64) {   // deg>64 tail (rare)
        int s = src_sorted[j];
        float e = as[s] + adn;
        e = e > 0.f ? e : 0.2f * e;
        m = fmaxf(m, e);
    }
    #pragma unroll
    for (int off = 32; off; off >>= 1) m = fmaxf(m, __shfl_xor(m, off));
    float p_lane = __expf(e_lane - m);                    // 0 for inactive lanes
    float denom = p_lane;
    for (int j = start + 64 + lane; j < end; j += 64) {   // rare
        int s = src_sorted[j];
        float e = as[s] + adn;
        e = e > 0.f ? e : 0.2f * e;
        denom += __expf(e - m);
    }
    #pragma unroll
    for (int off = 32; off; off >>= 1) denom += __shfl_xor(denom, off);
    float inv = 1.f / denom;
    p_lane *= inv;                                        // normalized weight

    // pass 3: lanes 0-31 -> even edge, lanes 32-63 -> odd edge; 16 B/lane
    const int half = lane >> 5;
    const int hl = lane & 31;
    float acc[8] = {0.f, 0.f, 0.f, 0.f, 0.f, 0.f, 0.f, 0.f};
    for (int j0 = 0; j0 < deg; j0 += 2) {
        int myj = j0 + half;
        int src_idx = min(myj, 63);
        float w = __shfl(p_lane, src_idx);
        int s = __shfl(s_lane, src_idx);
        bool valid = myj < deg;
        if (myj >= 64 && valid) {                         // rare tail
            s = src_sorted[start + myj];
            float e = as[s] + adn;
            e = e > 0.f ? e : 0.2f * e;
            w = __expf(e - m) * inv;
        }
        if (valid) {
            u16x8 row = *(const u16x8*)(h + (size_t)s * 256 + hl * 8);
            #pragma unroll
            for (int k = 0; k < 8; ++k) acc[k] += w * bf2f(row[k]);
        }
    }
    #pragma unroll
    for (int k = 0; k < 8; ++k) acc[k] += __shfl_xor(acc[k], 32);
    if (half == 0) {
        const float4* b4 = (const float4*)bias;
        float4 b0 = b4[hl * 2], b1 = b4[hl * 2 + 1];
        float v[8];
        v[0] = acc[0] + b0.x; v[1] = acc[1] + b0.y; v[2] = acc[2] + b0.z; v[3] = acc[3] + b0.w;
        v[4] = acc[4] + b1.x; v[5] = acc[5] + b1.y; v[6] = acc[6] + b1.z; v[7] = acc[7] + b1.w;
        if (ACT) {
            #pragma unroll
            for (int k = 0; k < 8; ++k) v[k] = v[k] > 0.f ? v[k] : 0.01f * v[k];
        }
        if (BF16OUT) {
            u16x8 o;
            #pragma unroll
            for (int k = 0; k < 8; ++k) o[k] = f2bf(v[k]);
            *(u16x8*)(out16 + (size_t)wv * 256 + hl * 8) = o;
        } else {
            float4 o0 = make_float4(v[0], v[1], v[2], v[3]);
            float4 o1 = make_float4(v[4], v[5], v[6], v[7]);
            float4* op = (float4*)(out + (size_t)wv * 256);
            op[hl * 2] = o0;
            op[hl * 2 + 1] = o1;
        }
    }
}

// ---------------- graph pooling (batch sorted; graph_emb pre-zeroed) -------
__global__ __launch_bounds__(256)
void pool_kernel(const float* __restrict__ node_emb, const int* __restrict__ batch,
                 float* __restrict__ graph_emb, int n) {
    int f = threadIdx.x;
    int chunk = (n + gridDim.x - 1) / gridDim.x;
    int i0 = blockIdx.x * chunk;
    int i1 = min(i0 + chunk, n);
    if (i0 >= i1) return;
    float acc = 0.f;
    int cur = batch[i0];
    for (int i = i0; i < i1; ++i) {
        int g = batch[i];
        if (g != cur) {
            atomicAdd(&graph_emb[(size_t)cur * 256 + f], acc);
            acc = 0.f; cur = g;
        }
        acc += node_emb[(size_t)i * 256 + f];
    }
    atomicAdd(&graph_emb[(size_t)cur * 256 + f], acc);
}

static inline char* align_up(char* p, size_t a) {
    return (char*)(((uintptr_t)p + a - 1) & ~(uintptr_t)(a - 1));
}

extern "C" void kernel_launch(void* const* d_in, const int* in_sizes, int n_in,
                              void* d_out, int out_size, void* d_ws, size_t ws_size,
                              hipStream_t stream) {
    const float* x     = (const float*)d_in[0];
    const int* eidx    = (const int*)d_in[1];   // [2, E]: row0=src, row1=dst
    const int* batch   = (const int*)d_in[2];
    const float* W1    = (const float*)d_in[3];
    const float* a_s1  = (const float*)d_in[4];
    const float* a_d1  = (const float*)d_in[5];
    const float* b1    = (const float*)d_in[6];
    const float* W2    = (const float*)d_in[7];
    const float* a_s2  = (const float*)d_in[8];
    const float* a_d2  = (const float*)d_in[9];
    const float* b2    = (const float*)d_in[10];

    float* node_emb  = (float*)d_out;                       // [NN, 256]
    float* graph_emb = node_emb + (size_t)NN * 256;         // [NG, 256]

    char* ws = (char*)d_ws;
    ushort* h16  = (ushort*)ws;  ws += (size_t)NN * 256 * sizeof(ushort);  // gemm out (bf16)
    ws = align_up(ws, 256);
    ushort* z16  = (ushort*)ws;  ws += (size_t)NN * 256 * sizeof(ushort);  // agg1 out (bf16)
    ws = align_up(ws, 256);
    ushort* wt1  = (ushort*)ws;  ws += (size_t)256 * F_IN * sizeof(ushort);
    ws = align_up(ws, 256);
    ushort* wt2  = (ushort*)ws;  ws += (size_t)256 * F_HID * sizeof(ushort);
    ws = align_up(ws, 256);
    float* as_buf = (float*)ws;  ws += (size_t)NN * sizeof(float);
    float* ad_buf = (float*)ws;  ws += (size_t)NN * sizeof(float);   // contiguous w/ as_buf
    int* counts   = (int*)ws;    ws += (size_t)NN * sizeof(int);
    int* offsets  = (int*)ws;    ws += (size_t)(NN + 1) * sizeof(int);
    ws = align_up(ws, 256);
    int* cursor   = (int*)ws;    ws += (size_t)NN * sizeof(int);
    int* bsum     = (int*)ws;    ws += (size_t)SCAN_NB * sizeof(int);
    int* boff     = (int*)ws;    ws += (size_t)SCAN_NB * sizeof(int);
    ws = align_up(ws, 256);
    int* src_sorted = (int*)ws;  ws += (size_t)(NE + NN) * sizeof(int);

    const int* e_src = eidx;
    const int* e_dst = eidx + NE;

    dim3 gemm_grid((NN + 127) / 128, 2);
    int node_waves_blocks = (NN + 3) / 4;   // 4 waves per 256-thread block

    // ---- CSR build (shared by both layers) ----
    hipMemsetAsync(counts, 0, (size_t)NN * sizeof(int), stream);
    hist_kernel<<<(NE + NN + 255) / 256, 256, 0, stream>>>(e_dst, counts, NE, NN);
    scan_partials<<<SCAN_NB, SCAN_B, 0, stream>>>(counts, bsum, NN);
    scan_block_sums<<<1, 256, 0, stream>>>(bsum, boff, offsets + NN, SCAN_NB, NN);
    scan_final<<<SCAN_NB, SCAN_B, 0, stream>>>(counts, boff, offsets, cursor, NN);
    scatter_kernel<<<(NE + NN + 255) / 256, 256, 0, stream>>>(e_src, e_dst, cursor, src_sorted, NE, NN);

    // ---- weight conversions (one launch) ----
    cvt_wts<<<(256 * (F_IN + F_HID) + 255) / 256, 256, 0, stream>>>(W1, wt1, W2, wt2);

    // ---- layer 1 (A = fp32 x, converted in gemm) ----
    hipMemsetAsync(as_buf, 0, (size_t)2 * NN * sizeof(float), stream);
    gemm_mfma<F_IN, true><<<gemm_grid, 256, 0, stream>>>(x, wt1, h16, a_s1, a_d1, as_buf, ad_buf, NN);
    agg_kernel<true, true><<<node_waves_blocks, 256, 0, stream>>>(h16, as_buf, ad_buf, offsets,
                                                                  src_sorted, b1, nullptr, z16, NN);
    // ---- layer 2 ----
    hipMemsetAsync(as_buf, 0, (size_t)2 * NN * sizeof(float), stream);
    gemm_mfma<F_HID, false><<<gemm_grid, 256, 0, stream>>>(z16, wt2, h16, a_s2, a_d2, as_buf, ad_buf, NN);
    agg_kernel<false, false><<<node_waves_blocks, 256, 0, stream>>>(h16, as_buf, ad_buf, offsets,
                                                                    src_sorted, b2, node_emb, nullptr, NN);
    // ---- pool ----
    hipMemsetAsync(graph_emb, 0, (size_t)NG * 256 * sizeof(float), stream);
    pool_kernel<<<1024, 256, 0, stream>>>(node_emb, batch, graph_emb, NN);
}